// Round 1
// baseline (194.198 us; speedup 1.0000x reference)
//
#include <hip/hip_runtime.h>
#include <hip/hip_bf16.h>

typedef __bf16 bf16x8 __attribute__((ext_vector_type(8)));
typedef float  f32x4  __attribute__((ext_vector_type(4)));
typedef unsigned short u16x8 __attribute__((ext_vector_type(8)));
typedef unsigned short us4   __attribute__((ext_vector_type(4)));

#define HH    8
#define NN    4096
#define FIN   512
#define FOUT  64
#define ALPHA 0.2f

// ---------------------------------------------------------------------------
// k0: W[h][f][o] (fp32) -> WT[h][o][f] (bf16), coalesced via LDS 64x64 tile.
// ---------------------------------------------------------------------------
__global__ __launch_bounds__(256) void k_transpose_w(
    const float* __restrict__ Wsrc, __hip_bfloat16* __restrict__ WT) {
    __shared__ __hip_bfloat16 lt[64][65];
    const int h  = blockIdx.x >> 3;
    const int f0 = (blockIdx.x & 7) * 64;
    const int tid = threadIdx.x;
#pragma unroll
    for (int p = 0; p < 16; ++p) {
        int f = p * 4 + (tid >> 6);
        int o = tid & 63;
        lt[f][o] = __float2bfloat16(Wsrc[((size_t)h * FIN + f0 + f) * FOUT + o]);
    }
    __syncthreads();
#pragma unroll
    for (int p = 0; p < 16; ++p) {
        int o = p * 4 + (tid >> 6);
        int f = tid & 63;
        WT[((size_t)h * FOUT + o) * FIN + f0 + f] = lt[f][o];
    }
}

// ---------------------------------------------------------------------------
// k_prep: FUSED adjacency bit-pack + projection (independent work).
// Blocks [0,2048): in-place pack — block b owns rows 2b,2b+1; first 1 KB of
//   its 32768-B region becomes bits (NOT contiguous across row-pairs).
// Blocks [2048,2304): projection: tile = pb&127 (32 rows), hgroup = pb>>7.
// ---------------------------------------------------------------------------
__global__ __launch_bounds__(256) void k_prep(
    int* __restrict__ adj,
    const float* __restrict__ feat,
    const __hip_bfloat16* __restrict__ WT,
    const float* __restrict__ a_src,
    const float* __restrict__ a_dst,
    unsigned short* __restrict__ WhT,
    float* __restrict__ srcv,
    unsigned short* __restrict__ Ebf, unsigned short* __restrict__ Fbf) {
    __shared__ alignas(16) __hip_bfloat16 lfeat[32][520];

    const int tid = threadIdx.x;

    if (blockIdx.x < 2048) {   // ---- pack path ----
        const size_t base = (size_t)blockIdx.x * 8192;
        unsigned m = 0;
#pragma unroll
        for (int p = 0; p < 8; ++p) {
            int4 v = *(const int4*)(adj + base + tid * 32 + p * 4);
            m |= (unsigned)(v.x > 0) << (p * 4);
            m |= (unsigned)(v.y > 0) << (p * 4 + 1);
            m |= (unsigned)(v.z > 0) << (p * 4 + 2);
            m |= (unsigned)(v.w > 0) << (p * 4 + 3);
        }
        __syncthreads();
        ((unsigned*)adj)[base + tid] = m;
        return;
    }

    // ---- projection path ----
    const int pb   = blockIdx.x - 2048;
    const int tile = pb & 127;            // 32 rows per block
    const int hgy  = pb >> 7;             // 0..1

#pragma unroll
    for (int p = 0; p < 16; ++p) {
        int idx  = p * 256 + tid;
        int row  = idx >> 7;
        int col4 = (idx & 127) * 4;
        float4 f = *(const float4*)(feat + (size_t)(tile * 32 + row) * FIN + col4);
        __hip_bfloat16* dst = &lfeat[row][col4];
        dst[0] = __float2bfloat16(f.x); dst[1] = __float2bfloat16(f.y);
        dst[2] = __float2bfloat16(f.z); dst[3] = __float2bfloat16(f.w);
    }
    __syncthreads();

    const int h     = hgy * 4 + (tid >> 6);
    const int lane  = tid & 63;
    const int row16 = lane & 15;
    const int quad  = lane >> 4;

    const unsigned short* WTu = (const unsigned short*)WT + (size_t)h * FOUT * FIN;

    f32x4 acc[2][4] = {};
    for (int k0 = 0; k0 < FIN; k0 += 32) {
        bf16x8 a0 = *(const bf16x8*)&lfeat[row16][k0 + quad * 8];
        bf16x8 a1 = *(const bf16x8*)&lfeat[16 + row16][k0 + quad * 8];
#pragma unroll
        for (int ot = 0; ot < 4; ++ot) {
            bf16x8 b = *(const bf16x8*)(WTu + (size_t)(ot * 16 + row16) * FIN + k0 + quad * 8);
            acc[0][ot] = __builtin_amdgcn_mfma_f32_16x16x32_bf16(a0, b, acc[0][ot], 0, 0, 0);
            acc[1][ot] = __builtin_amdgcn_mfma_f32_16x16x32_bf16(a1, b, acc[1][ot], 0, 0, 0);
        }
    }

#pragma unroll
    for (int g = 0; g < 2; ++g)
#pragma unroll
        for (int ot = 0; ot < 4; ++ot) {
            us4 u;
#pragma unroll
            for (int r = 0; r < 4; ++r)
                u[r] = __builtin_bit_cast(unsigned short, (__bf16)acc[g][ot][r]);
            *(us4*)(WhT + (size_t)(h * FOUT + ot * 16 + row16) * NN
                        + tile * 32 + g * 16 + quad * 4) = u;
        }

    float asv[4], adv[4];
#pragma unroll
    for (int ot = 0; ot < 4; ++ot) {
        asv[ot] = a_src[h * FOUT + ot * 16 + row16];
        adv[ot] = a_dst[h * FOUT + ot * 16 + row16];
    }
#pragma unroll
    for (int g = 0; g < 2; ++g)
#pragma unroll
        for (int r = 0; r < 4; ++r) {
            float ss = 0.f, dd = 0.f;
#pragma unroll
            for (int ot = 0; ot < 4; ++ot) {
                ss += acc[g][ot][r] * asv[ot];
                dd += acc[g][ot][r] * adv[ot];
            }
            ss += __shfl_xor(ss, 1); ss += __shfl_xor(ss, 2);
            ss += __shfl_xor(ss, 4); ss += __shfl_xor(ss, 8);
            dd += __shfl_xor(dd, 1); dd += __shfl_xor(dd, 2);
            dd += __shfl_xor(dd, 4); dd += __shfl_xor(dd, 8);
            if (row16 == 0) {
                int n = tile * 32 + g * 16 + quad * 4 + r;
                srcv[h * NN + n] = ss;
                __bf16 e = (__bf16)__expf(dd);
                __bf16 f = (__bf16)__expf(ALPHA * dd);
                Ebf[h * NN + n] = __builtin_bit_cast(unsigned short, e);
                Fbf[h * NN + n] = __builtin_bit_cast(unsigned short, f);
            }
        }
}

// ---------------------------------------------------------------------------
// k_flash v2: masked softmax attention + ELU.
// R12 theory: v1 (128 rows/wave, acc[8][4]=128 AGPR + 116 VGPR ≈ 244 regs)
// was capped at 2 waves/SIMD + 1 block/CU -> VALUBusy 48%, dur 57.7 µs while
// the VALU inst count itself only needs ~28 µs. Fix occupancy, not ops:
//   wave = 32 rows x 1024 j  (acc[2][4] = 32 AGPR, ~100 regs total)
//   block = 512 thr = 8 waves = 2 rowgroups(32 rows) x 4 jsegs(1024 j)
//   grid  = dim3(64, 8): 64-row tiles, 512 blocks -> 2 resident blocks/CU
//   __launch_bounds__(512, 4): cap 128 regs -> 4 waves/SIMD (16 waves/CU).
// Per-score math identical to v1: p = exp(LeakyReLU(s+d)) = max(Es*Ed, Fs*Fd)
// (exp monotone, exact); lsum accumulated in VALU from masked p.
// Mask: 64 rows x 132 dwords (33.8 KB) in LDS, unioned with 4 stash bufs
// (32x68 f32 each). Reduction: 4 segs -> depth-2 tree, 5 syncs (was 9).
// ---------------------------------------------------------------------------
__global__ __launch_bounds__(512, 4) void k_flash(
    const unsigned* __restrict__ maskp,
    const float* __restrict__ srcv,
    const unsigned short* __restrict__ Ebf,
    const unsigned short* __restrict__ Fbf,
    const unsigned short* __restrict__ WhT,
    float* __restrict__ out) {
    __shared__ float st[4][32 * 68];     // 34816 B; mask (33792 B) aliases st
    __shared__ float lds_l[4][32];

    unsigned* lmask = (unsigned*)&st[0][0];   // [64 rows][132 dwords]

    const int tid   = threadIdx.x;
    const int wav   = tid >> 6;               // 0..7
    const int rg    = wav >> 2;               // rowgroup 0..1 (32 rows each)
    const int seg   = wav & 3;                // jseg 0..3, 1024 j each
    const int lane  = tid & 63;
    const int row16 = lane & 15;
    const int quad  = lane >> 4;
    const int shl   = quad * 8;
    const int tile  = blockIdx.x;             // 64 rows
    const int h     = blockIdx.y;

    // ---- stage mask bits for 64 rows (32 row-pair chunks, 1 KB each)
#pragma unroll
    for (int p = 0; p < 4; ++p) {
        int tt = tid + p * 512;
        int c  = tt >> 6;                     // chunk 0..31
        int o  = (tt & 63) * 16;              // byte offset in chunk
        int4 v = *(const int4*)((const char*)maskp
                                + (size_t)(tile * 32 + c) * 32768 + o);
        int row = c * 2 + (o >> 9);
        int dw  = (o & 511) >> 2;
        *(int4*)&lmask[row * 132 + dw] = v;
    }
    __syncthreads();

    float Es[2], Fs[2];
#pragma unroll
    for (int g = 0; g < 2; ++g) {
        float si = srcv[h * NN + tile * 64 + rg * 32 + g * 16 + row16];
        Es[g] = __expf(si);
        Fs[g] = __expf(ALPHA * si);
    }
    const int mbase = (rg * 32 + row16) * 132 + seg * 32;   // + g*2112 + t

    const unsigned short* Eb = Ebf + h * NN + seg * 1024;
    const unsigned short* Fb = Fbf + h * NN + seg * 1024;
    const unsigned short* wh = WhT + (size_t)h * FOUT * NN + seg * 1024;

    f32x4 acc[2][4] = {};
    float lsum[2]   = {};

#pragma unroll 1
    for (int t = 0; t < 32; ++t) {
        int jj = t * 32 + shl;
        u16x8 ev = *(const u16x8*)(Eb + jj);
        u16x8 fv = *(const u16x8*)(Fb + jj);
        bf16x8 b[4];
#pragma unroll
        for (int ot = 0; ot < 4; ++ot)
            b[ot] = *(const bf16x8*)(wh + (size_t)(ot * 16 + row16) * NN + jj);

        float ef[8], ff[8];
#pragma unroll
        for (int k = 0; k < 8; ++k) {
            ef[k] = __uint_as_float((unsigned)ev[k] << 16);
            ff[k] = __uint_as_float((unsigned)fv[k] << 16);
        }

        unsigned mb0 = (lmask[mbase + t] >> shl) & 0xffu;
        unsigned mb1 = (lmask[mbase + 2112 + t] >> shl) & 0xffu;
        union { bf16x8 v8; __hip_bfloat162 h2[4]; } a0u, a1u;
#pragma unroll
        for (int kk = 0; kk < 4; ++kk) {
            const int ka = kk * 2, kb = ka + 1;
            float p0a = ((mb0 >> ka) & 1u) ? fmaxf(ef[ka] * Es[0], ff[ka] * Fs[0]) : 0.f;
            float p0b = ((mb0 >> kb) & 1u) ? fmaxf(ef[kb] * Es[0], ff[kb] * Fs[0]) : 0.f;
            float p1a = ((mb1 >> ka) & 1u) ? fmaxf(ef[ka] * Es[1], ff[ka] * Fs[1]) : 0.f;
            float p1b = ((mb1 >> kb) & 1u) ? fmaxf(ef[kb] * Es[1], ff[kb] * Fs[1]) : 0.f;
            lsum[0] += p0a + p0b;
            lsum[1] += p1a + p1b;
            a0u.h2[kk] = __float22bfloat162_rn(make_float2(p0a, p0b));
            a1u.h2[kk] = __float22bfloat162_rn(make_float2(p1a, p1b));
        }
#pragma unroll
        for (int ot = 0; ot < 4; ++ot) {
            acc[0][ot] = __builtin_amdgcn_mfma_f32_16x16x32_bf16(a0u.v8, b[ot], acc[0][ot], 0, 0, 0);
            acc[1][ot] = __builtin_amdgcn_mfma_f32_16x16x32_bf16(a1u.v8, b[ot], acc[1][ot], 0, 0, 0);
        }
    }

    // complete per-row sums across the 4 quads (disjoint k coverage)
#pragma unroll
    for (int g = 0; g < 2; ++g) {
        lsum[g] += __shfl_xor(lsum[g], 16);
        lsum[g] += __shfl_xor(lsum[g], 32);
    }

    __syncthreads();   // mask reads done; st[] may be reused as stash

    const int slot0 = rg * 2;

    auto stash = [&](int buf) {
#pragma unroll
        for (int g = 0; g < 2; ++g) {
#pragma unroll
            for (int ot = 0; ot < 4; ++ot)
#pragma unroll
                for (int r = 0; r < 4; ++r)
                    st[buf][(g * 16 + quad * 4 + r) * 68 + ot * 16 + row16] = acc[g][ot][r];
            if (quad == 0) lds_l[buf][g * 16 + row16] = lsum[g];
        }
    };
    auto addin = [&](int buf) {
#pragma unroll
        for (int g = 0; g < 2; ++g) {
#pragma unroll
            for (int ot = 0; ot < 4; ++ot)
#pragma unroll
                for (int r = 0; r < 4; ++r)
                    acc[g][ot][r] += st[buf][(g * 16 + quad * 4 + r) * 68 + ot * 16 + row16];
            lsum[g] += lds_l[buf][g * 16 + row16];
        }
    };

    if (seg == 1) stash(slot0);
    if (seg == 3) stash(slot0 + 1);
    __syncthreads();
    if (seg == 0) addin(slot0);
    if (seg == 2) addin(slot0 + 1);
    __syncthreads();
    if (seg == 2) stash(slot0);
    __syncthreads();
    if (seg == 0) {
        addin(slot0);
        // epilogue: divide by l, ELU, deposit final 64x64 tile into fin
        float* fin = &st[0][0];
#pragma unroll
        for (int g = 0; g < 2; ++g)
#pragma unroll
            for (int r = 0; r < 4; ++r) {
                int   qr  = quad * 4 + r;
                float l   = __shfl(lsum[g], qr);    // lane qr holds row qr's sum
                float rl  = 1.0f / l;
#pragma unroll
                for (int ot = 0; ot < 4; ++ot) {
                    float v = acc[g][ot][r] * rl;
                    float y = v > 0.f ? v : __expf(v) - 1.f;
                    fin[(rg * 32 + g * 16 + qr) * 68 + ot * 16 + row16] = y;
                }
            }
    }
    __syncthreads();
    // cooperative coalesced store: 1024 float4s by 512 threads
    const float* fin = &st[0][0];
#pragma unroll
    for (int p = 0; p < 2; ++p) {
        int f    = tid + p * 512;
        int row  = f >> 4;
        int col4 = (f & 15) * 4;
        float4 v = *(const float4*)&fin[row * 68 + col4];
        *(float4*)&out[(size_t)(tile * 64 + row) * (HH * FOUT) + h * FOUT + col4] = v;
    }
}

// ---------------------------------------------------------------------------
extern "C" void kernel_launch(void* const* d_in, const int* in_sizes, int n_in,
                              void* d_out, int out_size, void* d_ws, size_t ws_size,
                              hipStream_t stream) {
    const float* features = (const float*)d_in[0];
    int*         adj      = (int*)d_in[1];     // packed in place by k_prep
    const float* W        = (const float*)d_in[2];
    const float* a_src    = (const float*)d_in[3];
    const float* a_dst    = (const float*)d_in[4];
    float*       out      = (float*)d_out;

    // Workspace: exactly the proven 4.75 MB footprint
    char* ws = (char*)d_ws;
    __hip_bfloat16* WT   = (__hip_bfloat16*)(ws);                             // 512 KB
    unsigned short* WhT  = (unsigned short*)(ws + (512 << 10));               // 4 MB
    float*          srcv = (float*)(ws + (512 << 10) + (4 << 20));            // 128 KB
    unsigned short* Ebf  = (unsigned short*)(ws + (512 << 10) + (4 << 20) + (128 << 10));  // 64 KB
    unsigned short* Fbf  = (unsigned short*)(ws + (512 << 10) + (4 << 20) + (192 << 10));  // 64 KB

    k_transpose_w<<<dim3(64), 256, 0, stream>>>(W, WT);
    k_prep<<<dim3(2048 + 256), 256, 0, stream>>>(adj, features, WT, a_src, a_dst,
                                                 WhT, srcv, Ebf, Fbf);
    k_flash<<<dim3(64, 8), 512, 0, stream>>>((const unsigned*)adj, srcv, Ebf, Fbf,
                                             WhT, out);
}

// Round 2
// 169.872 us; speedup vs baseline: 1.1432x; 1.1432x over previous
//
#include <hip/hip_runtime.h>
#include <hip/hip_bf16.h>

typedef __bf16 bf16x8 __attribute__((ext_vector_type(8)));
typedef float  f32x4  __attribute__((ext_vector_type(4)));
typedef unsigned short u16x8 __attribute__((ext_vector_type(8)));
typedef unsigned short us4   __attribute__((ext_vector_type(4)));

#define HH    8
#define NN    4096
#define FIN   512
#define FOUT  64
#define ALPHA 0.2f

// ---------------------------------------------------------------------------
// k0: W[h][f][o] (fp32) -> WT[h][o][f] (bf16), coalesced via LDS 64x64 tile.
// ---------------------------------------------------------------------------
__global__ __launch_bounds__(256) void k_transpose_w(
    const float* __restrict__ Wsrc, __hip_bfloat16* __restrict__ WT) {
    __shared__ __hip_bfloat16 lt[64][65];
    const int h  = blockIdx.x >> 3;
    const int f0 = (blockIdx.x & 7) * 64;
    const int tid = threadIdx.x;
#pragma unroll
    for (int p = 0; p < 16; ++p) {
        int f = p * 4 + (tid >> 6);
        int o = tid & 63;
        lt[f][o] = __float2bfloat16(Wsrc[((size_t)h * FIN + f0 + f) * FOUT + o]);
    }
    __syncthreads();
#pragma unroll
    for (int p = 0; p < 16; ++p) {
        int o = p * 4 + (tid >> 6);
        int f = tid & 63;
        WT[((size_t)h * FOUT + o) * FIN + f0 + f] = lt[f][o];
    }
}

// ---------------------------------------------------------------------------
// k_prep: FUSED adjacency bit-pack + projection (independent work).
// Blocks [0,2048): in-place pack — block b owns rows 2b,2b+1; first 1 KB of
//   its 32768-B region becomes bits (NOT contiguous across row-pairs).
// Blocks [2048,2304): projection: tile = pb&127 (32 rows), hgroup = pb>>7.
// ---------------------------------------------------------------------------
__global__ __launch_bounds__(256) void k_prep(
    int* __restrict__ adj,
    const float* __restrict__ feat,
    const __hip_bfloat16* __restrict__ WT,
    const float* __restrict__ a_src,
    const float* __restrict__ a_dst,
    unsigned short* __restrict__ WhT,
    float* __restrict__ srcv,
    unsigned short* __restrict__ Ebf, unsigned short* __restrict__ Fbf) {
    __shared__ alignas(16) __hip_bfloat16 lfeat[32][520];

    const int tid = threadIdx.x;

    if (blockIdx.x < 2048) {   // ---- pack path ----
        const size_t base = (size_t)blockIdx.x * 8192;
        unsigned m = 0;
#pragma unroll
        for (int p = 0; p < 8; ++p) {
            int4 v = *(const int4*)(adj + base + tid * 32 + p * 4);
            m |= (unsigned)(v.x > 0) << (p * 4);
            m |= (unsigned)(v.y > 0) << (p * 4 + 1);
            m |= (unsigned)(v.z > 0) << (p * 4 + 2);
            m |= (unsigned)(v.w > 0) << (p * 4 + 3);
        }
        __syncthreads();
        ((unsigned*)adj)[base + tid] = m;
        return;
    }

    // ---- projection path ----
    const int pb   = blockIdx.x - 2048;
    const int tile = pb & 127;            // 32 rows per block
    const int hgy  = pb >> 7;             // 0..1

#pragma unroll
    for (int p = 0; p < 16; ++p) {
        int idx  = p * 256 + tid;
        int row  = idx >> 7;
        int col4 = (idx & 127) * 4;
        float4 f = *(const float4*)(feat + (size_t)(tile * 32 + row) * FIN + col4);
        __hip_bfloat16* dst = &lfeat[row][col4];
        dst[0] = __float2bfloat16(f.x); dst[1] = __float2bfloat16(f.y);
        dst[2] = __float2bfloat16(f.z); dst[3] = __float2bfloat16(f.w);
    }
    __syncthreads();

    const int h     = hgy * 4 + (tid >> 6);
    const int lane  = tid & 63;
    const int row16 = lane & 15;
    const int quad  = lane >> 4;

    const unsigned short* WTu = (const unsigned short*)WT + (size_t)h * FOUT * FIN;

    f32x4 acc[2][4] = {};
    for (int k0 = 0; k0 < FIN; k0 += 32) {
        bf16x8 a0 = *(const bf16x8*)&lfeat[row16][k0 + quad * 8];
        bf16x8 a1 = *(const bf16x8*)&lfeat[16 + row16][k0 + quad * 8];
#pragma unroll
        for (int ot = 0; ot < 4; ++ot) {
            bf16x8 b = *(const bf16x8*)(WTu + (size_t)(ot * 16 + row16) * FIN + k0 + quad * 8);
            acc[0][ot] = __builtin_amdgcn_mfma_f32_16x16x32_bf16(a0, b, acc[0][ot], 0, 0, 0);
            acc[1][ot] = __builtin_amdgcn_mfma_f32_16x16x32_bf16(a1, b, acc[1][ot], 0, 0, 0);
        }
    }

#pragma unroll
    for (int g = 0; g < 2; ++g)
#pragma unroll
        for (int ot = 0; ot < 4; ++ot) {
            us4 u;
#pragma unroll
            for (int r = 0; r < 4; ++r)
                u[r] = __builtin_bit_cast(unsigned short, (__bf16)acc[g][ot][r]);
            *(us4*)(WhT + (size_t)(h * FOUT + ot * 16 + row16) * NN
                        + tile * 32 + g * 16 + quad * 4) = u;
        }

    float asv[4], adv[4];
#pragma unroll
    for (int ot = 0; ot < 4; ++ot) {
        asv[ot] = a_src[h * FOUT + ot * 16 + row16];
        adv[ot] = a_dst[h * FOUT + ot * 16 + row16];
    }
#pragma unroll
    for (int g = 0; g < 2; ++g)
#pragma unroll
        for (int r = 0; r < 4; ++r) {
            float ss = 0.f, dd = 0.f;
#pragma unroll
            for (int ot = 0; ot < 4; ++ot) {
                ss += acc[g][ot][r] * asv[ot];
                dd += acc[g][ot][r] * adv[ot];
            }
            ss += __shfl_xor(ss, 1); ss += __shfl_xor(ss, 2);
            ss += __shfl_xor(ss, 4); ss += __shfl_xor(ss, 8);
            dd += __shfl_xor(dd, 1); dd += __shfl_xor(dd, 2);
            dd += __shfl_xor(dd, 4); dd += __shfl_xor(dd, 8);
            if (row16 == 0) {
                int n = tile * 32 + g * 16 + quad * 4 + r;
                srcv[h * NN + n] = ss;
                __bf16 e = (__bf16)__expf(dd);
                __bf16 f = (__bf16)__expf(ALPHA * dd);
                Ebf[h * NN + n] = __builtin_bit_cast(unsigned short, e);
                Fbf[h * NN + n] = __builtin_bit_cast(unsigned short, f);
            }
        }
}

// ---------------------------------------------------------------------------
// k_flash v3: masked softmax attention + ELU. M=128 rows/wave, j-split 8
// (the v1 structure — v2's 32-row waves lost row-amortization, −36%).
// R13 theory: v1's VALUBusy=48% was EXPOSED LATENCY, not op count: ev/fv are
// loaded at iter top and unpacked immediately (#pragma unroll 1) -> ~400 cyc
// vmem stall every iter, and the 2 co-resident waves run identical streams
// in lockstep so they stall TOGETHER. Fixes, keeping the v1 shape:
//   (1) ev/fv prefetched one t-iter ahead (+8 VGPR; 116+8 arch +128 acc ≈ 252
//       <= 256 -> still 2 waves/SIMD, no occupancy loss)
//   (2) per-wave t-loop rotation (start at seg*2): co-resident waves hit
//       their vmem bursts at different times; accumulation order-invariant
//   (3) mask LDS dwords read one gp ahead (hides ~120 cyc lgkm)
//   (4) s_setprio(1) around the MFMA cluster (T5; +4-7% on attn structures)
// p = exp(LeakyReLU(s+d)) = max(Es*Ed, Fs*Fd) (exp monotone, exact).
// Block = 512 thr = 8 waves = 1 head x 8 j-segs (512 j, 16 iters);
// grid dim3(32,8). Mask: 128 rows x 132 dwords in LDS (67.6 KB) unioned
// with 2 stash bufs (stride 68).
// ---------------------------------------------------------------------------
__global__ __launch_bounds__(512, 2) void k_flash(
    const unsigned* __restrict__ maskp,
    const float* __restrict__ srcv,
    const unsigned short* __restrict__ Ebf,
    const unsigned short* __restrict__ Fbf,
    const unsigned short* __restrict__ WhT,
    float* __restrict__ out) {
    __shared__ float st[2][128 * 68];    // 69632 B; mask aliases st during loop
    __shared__ float lds_l[2][128];

    unsigned* lmask = (unsigned*)&st[0][0];   // [128 rows][132 dwords]

    const int tid   = threadIdx.x;
    const int seg   = tid >> 6;               // 0..7, 512 j each
    const int lane  = tid & 63;
    const int row16 = lane & 15;
    const int quad  = lane >> 4;
    const int shl   = quad * 8;
    const int tile  = blockIdx.x;             // 128 rows
    const int h     = blockIdx.y;

    // ---- stage mask bits for 128 rows (64 row-pair chunks, 1 KB each)
#pragma unroll
    for (int p = 0; p < 8; ++p) {
        int tt = tid + p * 512;
        int c  = tt >> 6;
        int o  = (tt & 63) * 16;
        int4 v = *(const int4*)((const char*)maskp
                                + (size_t)(tile * 64 + c) * 32768 + o);
        int row = c * 2 + (o >> 9);
        int dw  = (o & 511) >> 2;
        *(int4*)&lmask[row * 132 + dw] = v;
    }
    __syncthreads();

    float Es[8], Fs[8];
#pragma unroll
    for (int g = 0; g < 8; ++g) {
        float si = srcv[h * NN + tile * 128 + g * 16 + row16];
        Es[g] = __expf(si);
        Fs[g] = __expf(ALPHA * si);
    }
    const int mbase = row16 * 132 + seg * 16;   // + g*2112 + t

    const unsigned short* Eb = Ebf + h * NN + seg * 512;
    const unsigned short* Fb = Fbf + h * NN + seg * 512;
    const unsigned short* wh = WhT + (size_t)h * FOUT * NN + seg * 512;

    f32x4 acc[8][4] = {};
    float lsum[8]   = {};

    // rotated start (stagger waves) + one-iter-ahead ev/fv prefetch
    int t = (seg * 2) & 15;
    u16x8 ev = *(const u16x8*)(Eb + t * 32 + shl);
    u16x8 fv = *(const u16x8*)(Fb + t * 32 + shl);

#pragma unroll 1
    for (int i = 0; i < 16; ++i) {
        const int tn = (t + 1) & 15;
        const int jj = t * 32 + shl;
        // issue next iter's E/F loads first (oldest in vmem queue)
        u16x8 evn = *(const u16x8*)(Eb + tn * 32 + shl);
        u16x8 fvn = *(const u16x8*)(Fb + tn * 32 + shl);
        bf16x8 b[4];
#pragma unroll
        for (int ot = 0; ot < 4; ++ot)
            b[ot] = *(const bf16x8*)(wh + (size_t)(ot * 16 + row16) * NN + jj);

        float ef[8], ff[8];
#pragma unroll
        for (int k = 0; k < 8; ++k) {
            ef[k] = __uint_as_float((unsigned)ev[k] << 16);
            ff[k] = __uint_as_float((unsigned)fv[k] << 16);
        }

        // mask dwords for gp0, then read one gp ahead inside the loop
        unsigned mcur0 = lmask[mbase + 0 * 2112 + t];
        unsigned mcur1 = lmask[mbase + 1 * 2112 + t];

#pragma unroll
        for (int gp = 0; gp < 4; ++gp) {      // g in pairs: caps live af regs
            const int g0 = gp * 2, g1 = g0 + 1;
            unsigned mnx0 = 0, mnx1 = 0;
            if (gp < 3) {
                mnx0 = lmask[mbase + (g0 + 2) * 2112 + t];
                mnx1 = lmask[mbase + (g1 + 2) * 2112 + t];
            }
            unsigned mb0 = (mcur0 >> shl) & 0xffu;
            unsigned mb1 = (mcur1 >> shl) & 0xffu;
            union { bf16x8 v8; __hip_bfloat162 h2[4]; } a0u, a1u;
#pragma unroll
            for (int kk = 0; kk < 4; ++kk) {
                const int ka = kk * 2, kb = ka + 1;
                float p0a = ((mb0 >> ka) & 1u) ? fmaxf(ef[ka] * Es[g0], ff[ka] * Fs[g0]) : 0.f;
                float p0b = ((mb0 >> kb) & 1u) ? fmaxf(ef[kb] * Es[g0], ff[kb] * Fs[g0]) : 0.f;
                float p1a = ((mb1 >> ka) & 1u) ? fmaxf(ef[ka] * Es[g1], ff[ka] * Fs[g1]) : 0.f;
                float p1b = ((mb1 >> kb) & 1u) ? fmaxf(ef[kb] * Es[g1], ff[kb] * Fs[g1]) : 0.f;
                lsum[g0] += p0a + p0b;
                lsum[g1] += p1a + p1b;
                a0u.h2[kk] = __float22bfloat162_rn(make_float2(p0a, p0b));
                a1u.h2[kk] = __float22bfloat162_rn(make_float2(p1a, p1b));
            }
            __builtin_amdgcn_s_setprio(1);
#pragma unroll
            for (int ot = 0; ot < 4; ++ot) {
                acc[g0][ot] = __builtin_amdgcn_mfma_f32_16x16x32_bf16(a0u.v8, b[ot], acc[g0][ot], 0, 0, 0);
                acc[g1][ot] = __builtin_amdgcn_mfma_f32_16x16x32_bf16(a1u.v8, b[ot], acc[g1][ot], 0, 0, 0);
            }
            __builtin_amdgcn_s_setprio(0);
            mcur0 = mnx0;
            mcur1 = mnx1;
        }
        ev = evn;
        fv = fvn;
        t = tn;
    }

    // complete per-row sums across the 4 quads (disjoint k coverage)
#pragma unroll
    for (int g = 0; g < 8; ++g) {
        lsum[g] += __shfl_xor(lsum[g], 16);
        lsum[g] += __shfl_xor(lsum[g], 32);
    }

    __syncthreads();   // mask reads done; st[] may be reused as stash

    auto stash = [&](int buf) {
#pragma unroll
        for (int g = 0; g < 8; ++g)
#pragma unroll
            for (int ot = 0; ot < 4; ++ot)
#pragma unroll
                for (int r = 0; r < 4; ++r)
                    st[buf][(g * 16 + quad * 4 + r) * 68 + ot * 16 + row16] = acc[g][ot][r];
        if (quad == 0)
#pragma unroll
            for (int g = 0; g < 8; ++g)
                lds_l[buf][g * 16 + row16] = lsum[g];
    };
    auto addin = [&](int buf) {
#pragma unroll
        for (int g = 0; g < 8; ++g) {
#pragma unroll
            for (int ot = 0; ot < 4; ++ot)
#pragma unroll
                for (int r = 0; r < 4; ++r)
                    acc[g][ot][r] += st[buf][(g * 16 + quad * 4 + r) * 68 + ot * 16 + row16];
            lsum[g] += lds_l[buf][g * 16 + row16];
        }
    };

    if (seg == 1) stash(0);
    if (seg == 3) stash(1);
    __syncthreads();
    if (seg == 0) addin(0);
    if (seg == 2) addin(1);
    __syncthreads();
    if (seg == 5) stash(0);
    if (seg == 7) stash(1);
    __syncthreads();
    if (seg == 4) addin(0);
    if (seg == 6) addin(1);
    __syncthreads();
    if (seg == 2) stash(0);
    if (seg == 6) stash(1);
    __syncthreads();
    if (seg == 0) addin(0);
    if (seg == 4) addin(1);
    __syncthreads();
    if (seg == 4) stash(0);
    __syncthreads();
    if (seg == 0) {
        addin(0);
        // epilogue: divide by l, ELU, deposit final tile into st[0]
#pragma unroll
        for (int g = 0; g < 8; ++g)
#pragma unroll
            for (int r = 0; r < 4; ++r) {
                int   qr  = quad * 4 + r;
                float l   = __shfl(lsum[g], qr);    // lane qr holds row qr's sum
                float rl  = 1.0f / l;
#pragma unroll
                for (int ot = 0; ot < 4; ++ot) {
                    float v = acc[g][ot][r] * rl;
                    float y = v > 0.f ? v : __expf(v) - 1.f;
                    st[0][(g * 16 + qr) * 68 + ot * 16 + row16] = y;
                }
            }
    }
    __syncthreads();
    // cooperative coalesced store: 2048 float4s by 512 threads
#pragma unroll
    for (int p = 0; p < 4; ++p) {
        int f    = tid + p * 512;
        int row  = f >> 4;
        int col4 = (f & 15) * 4;
        float4 v = *(const float4*)&st[0][row * 68 + col4];
        *(float4*)&out[(size_t)(tile * 128 + row) * (HH * FOUT) + h * FOUT + col4] = v;
    }
}

// ---------------------------------------------------------------------------
extern "C" void kernel_launch(void* const* d_in, const int* in_sizes, int n_in,
                              void* d_out, int out_size, void* d_ws, size_t ws_size,
                              hipStream_t stream) {
    const float* features = (const float*)d_in[0];
    int*         adj      = (int*)d_in[1];     // packed in place by k_prep
    const float* W        = (const float*)d_in[2];
    const float* a_src    = (const float*)d_in[3];
    const float* a_dst    = (const float*)d_in[4];
    float*       out      = (float*)d_out;

    // Workspace: exactly the proven 4.75 MB footprint
    char* ws = (char*)d_ws;
    __hip_bfloat16* WT   = (__hip_bfloat16*)(ws);                             // 512 KB
    unsigned short* WhT  = (unsigned short*)(ws + (512 << 10));               // 4 MB
    float*          srcv = (float*)(ws + (512 << 10) + (4 << 20));            // 128 KB
    unsigned short* Ebf  = (unsigned short*)(ws + (512 << 10) + (4 << 20) + (128 << 10));  // 64 KB
    unsigned short* Fbf  = (unsigned short*)(ws + (512 << 10) + (4 << 20) + (192 << 10));  // 64 KB

    k_transpose_w<<<dim3(64), 256, 0, stream>>>(W, WT);
    k_prep<<<dim3(2048 + 256), 256, 0, stream>>>(adj, features, WT, a_src, a_dst,
                                                 WhT, srcv, Ebf, Fbf);
    k_flash<<<dim3(32, 8), 512, 0, stream>>>((const unsigned*)adj, srcv, Ebf, Fbf,
                                             WhT, out);
}

// Round 3
// 167.474 us; speedup vs baseline: 1.1596x; 1.0143x over previous
//
#include <hip/hip_runtime.h>
#include <hip/hip_bf16.h>

typedef __bf16 bf16x8 __attribute__((ext_vector_type(8)));
typedef _Float16 f16x8 __attribute__((ext_vector_type(8)));
typedef _Float16 f16x2 __attribute__((ext_vector_type(2)));
typedef float  f32x4  __attribute__((ext_vector_type(4)));
typedef unsigned short u16x8 __attribute__((ext_vector_type(8)));
typedef unsigned short us4   __attribute__((ext_vector_type(4)));

#define HH    8
#define NN    4096
#define FIN   512
#define FOUT  64
#define ALPHA 0.2f

// ---------------------------------------------------------------------------
// k0: W[h][f][o] (fp32) -> WT[h][o][f] (bf16), coalesced via LDS 64x64 tile.
// (projection stays bf16; only post-projection tensors move to f16)
// ---------------------------------------------------------------------------
__global__ __launch_bounds__(256) void k_transpose_w(
    const float* __restrict__ Wsrc, __hip_bfloat16* __restrict__ WT) {
    __shared__ __hip_bfloat16 lt[64][65];
    const int h  = blockIdx.x >> 3;
    const int f0 = (blockIdx.x & 7) * 64;
    const int tid = threadIdx.x;
#pragma unroll
    for (int p = 0; p < 16; ++p) {
        int f = p * 4 + (tid >> 6);
        int o = tid & 63;
        lt[f][o] = __float2bfloat16(Wsrc[((size_t)h * FIN + f0 + f) * FOUT + o]);
    }
    __syncthreads();
#pragma unroll
    for (int p = 0; p < 16; ++p) {
        int o = p * 4 + (tid >> 6);
        int f = tid & 63;
        WT[((size_t)h * FOUT + o) * FIN + f0 + f] = lt[f][o];
    }
}

// ---------------------------------------------------------------------------
// k_prep: FUSED adjacency bit-pack + projection (independent work).
// Blocks [0,2048): in-place pack — block b owns rows 2b,2b+1; first 1 KB of
//   its 32768-B region becomes bits (NOT contiguous across row-pairs).
// Blocks [2048,2304): projection: tile = pb&127 (32 rows), hgroup = pb>>7.
// R14 change: WhT / Ebf / Fbf are stored as IEEE f16 (not bf16) so k_flash
// can run a packed-f16 score pipeline. Range audit: s,d ~ N(0,1);
// exp(s),exp(d) <= ~150, products <= ~5e3 << 65504 (f16 max). More mantissa
// than bf16 -> accuracy strictly improves.
// ---------------------------------------------------------------------------
__global__ __launch_bounds__(256) void k_prep(
    int* __restrict__ adj,
    const float* __restrict__ feat,
    const __hip_bfloat16* __restrict__ WT,
    const float* __restrict__ a_src,
    const float* __restrict__ a_dst,
    unsigned short* __restrict__ WhT,
    float* __restrict__ srcv,
    unsigned short* __restrict__ Ebf, unsigned short* __restrict__ Fbf) {
    __shared__ alignas(16) __hip_bfloat16 lfeat[32][520];

    const int tid = threadIdx.x;

    if (blockIdx.x < 2048) {   // ---- pack path ----
        const size_t base = (size_t)blockIdx.x * 8192;
        unsigned m = 0;
#pragma unroll
        for (int p = 0; p < 8; ++p) {
            int4 v = *(const int4*)(adj + base + tid * 32 + p * 4);
            m |= (unsigned)(v.x > 0) << (p * 4);
            m |= (unsigned)(v.y > 0) << (p * 4 + 1);
            m |= (unsigned)(v.z > 0) << (p * 4 + 2);
            m |= (unsigned)(v.w > 0) << (p * 4 + 3);
        }
        __syncthreads();
        ((unsigned*)adj)[base + tid] = m;
        return;
    }

    // ---- projection path ----
    const int pb   = blockIdx.x - 2048;
    const int tile = pb & 127;            // 32 rows per block
    const int hgy  = pb >> 7;             // 0..1

#pragma unroll
    for (int p = 0; p < 16; ++p) {
        int idx  = p * 256 + tid;
        int row  = idx >> 7;
        int col4 = (idx & 127) * 4;
        float4 f = *(const float4*)(feat + (size_t)(tile * 32 + row) * FIN + col4);
        __hip_bfloat16* dst = &lfeat[row][col4];
        dst[0] = __float2bfloat16(f.x); dst[1] = __float2bfloat16(f.y);
        dst[2] = __float2bfloat16(f.z); dst[3] = __float2bfloat16(f.w);
    }
    __syncthreads();

    const int h     = hgy * 4 + (tid >> 6);
    const int lane  = tid & 63;
    const int row16 = lane & 15;
    const int quad  = lane >> 4;

    const unsigned short* WTu = (const unsigned short*)WT + (size_t)h * FOUT * FIN;

    f32x4 acc[2][4] = {};
    for (int k0 = 0; k0 < FIN; k0 += 32) {
        bf16x8 a0 = *(const bf16x8*)&lfeat[row16][k0 + quad * 8];
        bf16x8 a1 = *(const bf16x8*)&lfeat[16 + row16][k0 + quad * 8];
#pragma unroll
        for (int ot = 0; ot < 4; ++ot) {
            bf16x8 b = *(const bf16x8*)(WTu + (size_t)(ot * 16 + row16) * FIN + k0 + quad * 8);
            acc[0][ot] = __builtin_amdgcn_mfma_f32_16x16x32_bf16(a0, b, acc[0][ot], 0, 0, 0);
            acc[1][ot] = __builtin_amdgcn_mfma_f32_16x16x32_bf16(a1, b, acc[1][ot], 0, 0, 0);
        }
    }

#pragma unroll
    for (int g = 0; g < 2; ++g)
#pragma unroll
        for (int ot = 0; ot < 4; ++ot) {
            us4 u;
#pragma unroll
            for (int r = 0; r < 4; ++r)
                u[r] = __builtin_bit_cast(unsigned short, (_Float16)acc[g][ot][r]);
            *(us4*)(WhT + (size_t)(h * FOUT + ot * 16 + row16) * NN
                        + tile * 32 + g * 16 + quad * 4) = u;
        }

    float asv[4], adv[4];
#pragma unroll
    for (int ot = 0; ot < 4; ++ot) {
        asv[ot] = a_src[h * FOUT + ot * 16 + row16];
        adv[ot] = a_dst[h * FOUT + ot * 16 + row16];
    }
#pragma unroll
    for (int g = 0; g < 2; ++g)
#pragma unroll
        for (int r = 0; r < 4; ++r) {
            float ss = 0.f, dd = 0.f;
#pragma unroll
            for (int ot = 0; ot < 4; ++ot) {
                ss += acc[g][ot][r] * asv[ot];
                dd += acc[g][ot][r] * adv[ot];
            }
            ss += __shfl_xor(ss, 1); ss += __shfl_xor(ss, 2);
            ss += __shfl_xor(ss, 4); ss += __shfl_xor(ss, 8);
            dd += __shfl_xor(dd, 1); dd += __shfl_xor(dd, 2);
            dd += __shfl_xor(dd, 4); dd += __shfl_xor(dd, 8);
            if (row16 == 0) {
                int n = tile * 32 + g * 16 + quad * 4 + r;
                srcv[h * NN + n] = ss;
                _Float16 e = (_Float16)__expf(dd);
                _Float16 f = (_Float16)__expf(ALPHA * dd);
                Ebf[h * NN + n] = __builtin_bit_cast(unsigned short, e);
                Fbf[h * NN + n] = __builtin_bit_cast(unsigned short, f);
            }
        }
}

// ---------------------------------------------------------------------------
// k_flash v4: masked softmax attention + ELU — packed-f16 pipeline.
// R14 theory: VALUBusy/MfmaUtil are gfx94x-formula (4cyc/inst) -> real VALU
// time in v3 was ~14 µs of 54 -> the kernel is DEPENDENCY-STALL-bound at
// 2 waves/SIMD, and v1's grid (256 blocks) could never exceed 1 block/CU.
// Fix both op count and occupancy:
//   * f16 everywhere post-projection: per 2 scores = pk_mul, pk_mul, pk_max,
//     sbfe, sbfe, bfi(mask word), and, dot2(lsum)  — vs ~15 f32-scalar ops.
//     No unpack (packed ev/fv used directly), no cvt_pk (masked word IS the
//     mfma_f32_16x16x32_f16 A-fragment). Masked f16 inf -> AND-zeroed.
//   * wave = 64 rows x 512 j: acc[4][4] = 64 AGPR, ~60 arch VGPR -> <=128
//     total -> __launch_bounds__(512,4) = 4 waves/SIMD; grid (64,8) = 512
//     blocks = 2 blocks/CU. Amortization 32 scores/lane/iter (not v2's 16).
//   * keep: t-loop rotation stagger, setprio around MFMA cluster.
// Mask: 64 rows x 132 dwords (33.8 KB) aliasing 2 stash bufs (64x68 f32);
// reduction = v1's proven 7-phase tree. LDS 35328 B.
// Predicted: Occupancy ~40%, dur 54 -> 25-32 µs. Watch: VGPR=128/scratch
// => spilled; occupancy stuck at 20% => trim live ranges next.
// ---------------------------------------------------------------------------
__global__ __launch_bounds__(512, 4) void k_flash(
    const unsigned* __restrict__ maskp,
    const float* __restrict__ srcv,
    const unsigned short* __restrict__ Ebf,
    const unsigned short* __restrict__ Fbf,
    const unsigned short* __restrict__ WhT,
    float* __restrict__ out) {
    __shared__ float st[2][64 * 68];     // 34816 B; mask (33792 B) aliases st
    __shared__ float lds_l[2][64];

    unsigned* lmask = (unsigned*)&st[0][0];   // [64 rows][132 dwords]

    const int tid   = threadIdx.x;
    const int seg   = tid >> 6;               // 0..7, 512 j each
    const int lane  = tid & 63;
    const int row16 = lane & 15;
    const int quad  = lane >> 4;
    const int shl   = quad * 8;
    const int tile  = blockIdx.x;             // 64 rows
    const int h     = blockIdx.y;

    // ---- stage mask bits for 64 rows (32 row-pair chunks, 1 KB each)
#pragma unroll
    for (int p = 0; p < 4; ++p) {
        int tt = tid + p * 512;
        int c  = tt >> 6;                     // chunk 0..31
        int o  = (tt & 63) * 16;              // byte offset in chunk
        int4 v = *(const int4*)((const char*)maskp
                                + (size_t)(tile * 32 + c) * 32768 + o);
        int row = c * 2 + (o >> 9);
        int dw  = (o & 511) >> 2;
        *(int4*)&lmask[row * 132 + dw] = v;
    }
    __syncthreads();

    // per-row src factors, packed f16x2 (both halves equal)
    f16x2 Es2[4], Fs2[4];
#pragma unroll
    for (int g = 0; g < 4; ++g) {
        float si = srcv[h * NN + tile * 64 + g * 16 + row16];
        _Float16 e = (_Float16)__expf(si);
        _Float16 f = (_Float16)__expf(ALPHA * si);
        Es2[g][0] = e; Es2[g][1] = e;
        Fs2[g][0] = f; Fs2[g][1] = f;
    }
    const int mbase = row16 * 132 + seg * 16;   // + g*2112 + t

    const unsigned short* Eb = Ebf + h * NN + seg * 512;
    const unsigned short* Fb = Fbf + h * NN + seg * 512;
    const unsigned short* wh = WhT + (size_t)h * FOUT * NN + seg * 512;

    f32x4 acc[4][4] = {};
    float lsum[4]   = {};
    const f16x2 ones2 = {(_Float16)1.0f, (_Float16)1.0f};

    // rotated start: co-resident waves hit vmem bursts at different times
    int t = (seg * 2) & 15;

#pragma unroll 1
    for (int i = 0; i < 16; ++i) {
        const int jj = t * 32 + shl;
        union { f16x8 v8; f16x2 h2[4]; } evu, fvu;
        evu.v8 = *(const f16x8*)(Eb + jj);
        fvu.v8 = *(const f16x8*)(Fb + jj);
        f16x8 b[4];
#pragma unroll
        for (int ot = 0; ot < 4; ++ot)
            b[ot] = *(const f16x8*)(wh + (size_t)(ot * 16 + row16) * NN + jj);

#pragma unroll
        for (int g = 0; g < 4; ++g) {
            unsigned mb = lmask[mbase + g * 2112 + t] >> shl;   // bits 0..7
            union { f16x8 v8; unsigned w[4]; } au;
#pragma unroll
            for (int kk = 0; kk < 4; ++kk) {
                f16x2 t0 = evu.h2[kk] * Es2[g];
                f16x2 t1 = fvu.h2[kk] * Fs2[g];
                f16x2 p2 = __builtin_elementwise_max(t0, t1);
                // mask word: bit 2kk -> 0xFFFF (lo half), bit 2kk+1 -> hi half
                unsigned lo = (unsigned)__builtin_amdgcn_sbfe((int)mb, 2 * kk, 1);
                unsigned hi = (unsigned)__builtin_amdgcn_sbfe((int)mb, 2 * kk + 1, 1);
                unsigned w  = (lo & 0xFFFFu) | (hi & 0xFFFF0000u);   // v_bfi
                unsigned pw = __builtin_bit_cast(unsigned, p2) & w;
                f16x2 mp2   = __builtin_bit_cast(f16x2, pw);
                au.w[kk] = pw;
#if __has_builtin(__builtin_amdgcn_fdot2)
                lsum[g] = __builtin_amdgcn_fdot2(mp2, ones2, lsum[g], false);
#else
                lsum[g] += (float)mp2[0] + (float)mp2[1];
#endif
            }
            __builtin_amdgcn_s_setprio(1);
#pragma unroll
            for (int ot = 0; ot < 4; ++ot)
                acc[g][ot] = __builtin_amdgcn_mfma_f32_16x16x32_f16(au.v8, b[ot], acc[g][ot], 0, 0, 0);
            __builtin_amdgcn_s_setprio(0);
        }
        t = (t + 1) & 15;
    }

    // complete per-row sums across the 4 quads (disjoint k coverage)
#pragma unroll
    for (int g = 0; g < 4; ++g) {
        lsum[g] += __shfl_xor(lsum[g], 16);
        lsum[g] += __shfl_xor(lsum[g], 32);
    }

    __syncthreads();   // mask reads done; st[] may be reused as stash

    auto stash = [&](int buf) {
#pragma unroll
        for (int g = 0; g < 4; ++g)
#pragma unroll
            for (int ot = 0; ot < 4; ++ot)
#pragma unroll
                for (int r = 0; r < 4; ++r)
                    st[buf][(g * 16 + quad * 4 + r) * 68 + ot * 16 + row16] = acc[g][ot][r];
        if (quad == 0)
#pragma unroll
            for (int g = 0; g < 4; ++g)
                lds_l[buf][g * 16 + row16] = lsum[g];
    };
    auto addin = [&](int buf) {
#pragma unroll
        for (int g = 0; g < 4; ++g) {
#pragma unroll
            for (int ot = 0; ot < 4; ++ot)
#pragma unroll
                for (int r = 0; r < 4; ++r)
                    acc[g][ot][r] += st[buf][(g * 16 + quad * 4 + r) * 68 + ot * 16 + row16];
            lsum[g] += lds_l[buf][g * 16 + row16];
        }
    };

    if (seg == 1) stash(0);
    if (seg == 3) stash(1);
    __syncthreads();
    if (seg == 0) addin(0);
    if (seg == 2) addin(1);
    __syncthreads();
    if (seg == 5) stash(0);
    if (seg == 7) stash(1);
    __syncthreads();
    if (seg == 4) addin(0);
    if (seg == 6) addin(1);
    __syncthreads();
    if (seg == 2) stash(0);
    if (seg == 6) stash(1);
    __syncthreads();
    if (seg == 0) addin(0);
    if (seg == 4) addin(1);
    __syncthreads();
    if (seg == 4) stash(0);
    __syncthreads();
    if (seg == 0) {
        addin(0);
        // epilogue: divide by l, ELU, deposit final 64x64 tile into st[0]
#pragma unroll
        for (int g = 0; g < 4; ++g)
#pragma unroll
            for (int r = 0; r < 4; ++r) {
                int   qr  = quad * 4 + r;
                float l   = __shfl(lsum[g], qr);    // lane qr holds row qr's sum
                float rl  = 1.0f / l;
#pragma unroll
                for (int ot = 0; ot < 4; ++ot) {
                    float v = acc[g][ot][r] * rl;
                    float y = v > 0.f ? v : __expf(v) - 1.f;
                    st[0][(g * 16 + qr) * 68 + ot * 16 + row16] = y;
                }
            }
    }
    __syncthreads();
    // cooperative coalesced store: 1024 float4s by 512 threads
#pragma unroll
    for (int p = 0; p < 2; ++p) {
        int f    = tid + p * 512;
        int row  = f >> 4;
        int col4 = (f & 15) * 4;
        float4 v = *(const float4*)&st[0][row * 68 + col4];
        *(float4*)&out[(size_t)(tile * 64 + row) * (HH * FOUT) + h * FOUT + col4] = v;
    }
}

// ---------------------------------------------------------------------------
extern "C" void kernel_launch(void* const* d_in, const int* in_sizes, int n_in,
                              void* d_out, int out_size, void* d_ws, size_t ws_size,
                              hipStream_t stream) {
    const float* features = (const float*)d_in[0];
    int*         adj      = (int*)d_in[1];     // packed in place by k_prep
    const float* W        = (const float*)d_in[2];
    const float* a_src    = (const float*)d_in[3];
    const float* a_dst    = (const float*)d_in[4];
    float*       out      = (float*)d_out;

    // Workspace: exactly the proven 4.75 MB footprint
    char* ws = (char*)d_ws;
    __hip_bfloat16* WT   = (__hip_bfloat16*)(ws);                             // 512 KB
    unsigned short* WhT  = (unsigned short*)(ws + (512 << 10));               // 4 MB (f16)
    float*          srcv = (float*)(ws + (512 << 10) + (4 << 20));            // 128 KB
    unsigned short* Ebf  = (unsigned short*)(ws + (512 << 10) + (4 << 20) + (128 << 10));  // 64 KB (f16)
    unsigned short* Fbf  = (unsigned short*)(ws + (512 << 10) + (4 << 20) + (192 << 10));  // 64 KB (f16)

    k_transpose_w<<<dim3(64), 256, 0, stream>>>(W, WT);
    k_prep<<<dim3(2048 + 256), 256, 0, stream>>>(adj, features, WT, a_src, a_dst,
                                                 WhT, srcv, Ebf, Fbf);
    k_flash<<<dim3(64, 8), 512, 0, stream>>>((const unsigned*)adj, srcv, Ebf, Fbf,
                                             WhT, out);
}

// Round 4
// 164.451 us; speedup vs baseline: 1.1809x; 1.0184x over previous
//
#include <hip/hip_runtime.h>
#include <hip/hip_bf16.h>

typedef __bf16 bf16x8 __attribute__((ext_vector_type(8)));
typedef _Float16 f16x8 __attribute__((ext_vector_type(8)));
typedef _Float16 f16x2 __attribute__((ext_vector_type(2)));
typedef float  f32x4  __attribute__((ext_vector_type(4)));
typedef unsigned short u16x8 __attribute__((ext_vector_type(8)));
typedef unsigned short us4   __attribute__((ext_vector_type(4)));

#define HH    8
#define NN    4096
#define FIN   512
#define FOUT  64
#define ALPHA 0.2f

// ---------------------------------------------------------------------------
// k0: W[h][f][o] (fp32) -> WT[h][o][f] (bf16), coalesced via LDS 64x64 tile.
// ---------------------------------------------------------------------------
__global__ __launch_bounds__(256) void k_transpose_w(
    const float* __restrict__ Wsrc, __hip_bfloat16* __restrict__ WT) {
    __shared__ __hip_bfloat16 lt[64][65];
    const int h  = blockIdx.x >> 3;
    const int f0 = (blockIdx.x & 7) * 64;
    const int tid = threadIdx.x;
#pragma unroll
    for (int p = 0; p < 16; ++p) {
        int f = p * 4 + (tid >> 6);
        int o = tid & 63;
        lt[f][o] = __float2bfloat16(Wsrc[((size_t)h * FIN + f0 + f) * FOUT + o]);
    }
    __syncthreads();
#pragma unroll
    for (int p = 0; p < 16; ++p) {
        int o = p * 4 + (tid >> 6);
        int f = tid & 63;
        WT[((size_t)h * FOUT + o) * FIN + f0 + f] = lt[f][o];
    }
}

// ---------------------------------------------------------------------------
// k_prep: FUSED adjacency bit-pack + projection (independent work).
// R15 change: pack no longer clobbers adj. Blocks [0,2048): block b reads
// rows 2b,2b+1 (32 KB) and writes 256 packed dwords to maskdst at
// b*mstride dwords. With the ws buffer, mstride=256 (contiguous 2 MB);
// fallback mstride=8192 packs in place (old layout). Rationale: the harness
// restores any written input every timed iteration (in-place pack passes on
// replay => restore exists) — a ~64 MB adj restore sat inside the timed
// region. Read-only inputs avoid it.
// Blocks [2048,2304): projection (f16 WhT/Ebf/Fbf outputs).
// ---------------------------------------------------------------------------
__global__ __launch_bounds__(256) void k_prep(
    const int* __restrict__ adj,
    unsigned* __restrict__ maskdst, int mstride,
    const float* __restrict__ feat,
    const __hip_bfloat16* __restrict__ WT,
    const float* __restrict__ a_src,
    const float* __restrict__ a_dst,
    unsigned short* __restrict__ WhT,
    float* __restrict__ srcv,
    unsigned short* __restrict__ Ebf, unsigned short* __restrict__ Fbf) {
    __shared__ alignas(16) __hip_bfloat16 lfeat[32][520];

    const int tid = threadIdx.x;

    if (blockIdx.x < 2048) {   // ---- pack path ----
        const size_t base = (size_t)blockIdx.x * 8192;
        unsigned m = 0;
#pragma unroll
        for (int p = 0; p < 8; ++p) {
            int4 v = *(const int4*)(adj + base + tid * 32 + p * 4);
            m |= (unsigned)(v.x > 0) << (p * 4);
            m |= (unsigned)(v.y > 0) << (p * 4 + 1);
            m |= (unsigned)(v.z > 0) << (p * 4 + 2);
            m |= (unsigned)(v.w > 0) << (p * 4 + 3);
        }
        __syncthreads();   // needed only for in-place fallback; cheap
        maskdst[(size_t)blockIdx.x * mstride + tid] = m;
        return;
    }

    // ---- projection path ----
    const int pb   = blockIdx.x - 2048;
    const int tile = pb & 127;            // 32 rows per block
    const int hgy  = pb >> 7;             // 0..1

#pragma unroll
    for (int p = 0; p < 16; ++p) {
        int idx  = p * 256 + tid;
        int row  = idx >> 7;
        int col4 = (idx & 127) * 4;
        float4 f = *(const float4*)(feat + (size_t)(tile * 32 + row) * FIN + col4);
        __hip_bfloat16* dst = &lfeat[row][col4];
        dst[0] = __float2bfloat16(f.x); dst[1] = __float2bfloat16(f.y);
        dst[2] = __float2bfloat16(f.z); dst[3] = __float2bfloat16(f.w);
    }
    __syncthreads();

    const int h     = hgy * 4 + (tid >> 6);
    const int lane  = tid & 63;
    const int row16 = lane & 15;
    const int quad  = lane >> 4;

    const unsigned short* WTu = (const unsigned short*)WT + (size_t)h * FOUT * FIN;

    f32x4 acc[2][4] = {};
    for (int k0 = 0; k0 < FIN; k0 += 32) {
        bf16x8 a0 = *(const bf16x8*)&lfeat[row16][k0 + quad * 8];
        bf16x8 a1 = *(const bf16x8*)&lfeat[16 + row16][k0 + quad * 8];
#pragma unroll
        for (int ot = 0; ot < 4; ++ot) {
            bf16x8 b = *(const bf16x8*)(WTu + (size_t)(ot * 16 + row16) * FIN + k0 + quad * 8);
            acc[0][ot] = __builtin_amdgcn_mfma_f32_16x16x32_bf16(a0, b, acc[0][ot], 0, 0, 0);
            acc[1][ot] = __builtin_amdgcn_mfma_f32_16x16x32_bf16(a1, b, acc[1][ot], 0, 0, 0);
        }
    }

#pragma unroll
    for (int g = 0; g < 2; ++g)
#pragma unroll
        for (int ot = 0; ot < 4; ++ot) {
            us4 u;
#pragma unroll
            for (int r = 0; r < 4; ++r)
                u[r] = __builtin_bit_cast(unsigned short, (_Float16)acc[g][ot][r]);
            *(us4*)(WhT + (size_t)(h * FOUT + ot * 16 + row16) * NN
                        + tile * 32 + g * 16 + quad * 4) = u;
        }

    float asv[4], adv[4];
#pragma unroll
    for (int ot = 0; ot < 4; ++ot) {
        asv[ot] = a_src[h * FOUT + ot * 16 + row16];
        adv[ot] = a_dst[h * FOUT + ot * 16 + row16];
    }
#pragma unroll
    for (int g = 0; g < 2; ++g)
#pragma unroll
        for (int r = 0; r < 4; ++r) {
            float ss = 0.f, dd = 0.f;
#pragma unroll
            for (int ot = 0; ot < 4; ++ot) {
                ss += acc[g][ot][r] * asv[ot];
                dd += acc[g][ot][r] * adv[ot];
            }
            ss += __shfl_xor(ss, 1); ss += __shfl_xor(ss, 2);
            ss += __shfl_xor(ss, 4); ss += __shfl_xor(ss, 8);
            dd += __shfl_xor(dd, 1); dd += __shfl_xor(dd, 2);
            dd += __shfl_xor(dd, 4); dd += __shfl_xor(dd, 8);
            if (row16 == 0) {
                int n = tile * 32 + g * 16 + quad * 4 + r;
                srcv[h * NN + n] = ss;
                _Float16 e = (_Float16)__expf(dd);
                _Float16 f = (_Float16)__expf(ALPHA * dd);
                Ebf[h * NN + n] = __builtin_bit_cast(unsigned short, e);
                Fbf[h * NN + n] = __builtin_bit_cast(unsigned short, f);
            }
        }
}

// ---------------------------------------------------------------------------
// k_flash v5: packed-f16 masked softmax attention + ELU.
// R15 theory: v4 was ~75% dependency-stall (real VALU ~7 µs, MFMA ~6.5 µs,
// HBM ~3 µs of 51) because the 128-reg/4-wave cap left no room to prefetch —
// every iter exposed full vmem latency. 512-thr blocks quantize occupancy
// (>128 regs -> 1 block/CU -> 2 waves/SIMD). Fix: 256-thr blocks.
//   * block = 256 thr = 4 waves = 4 j-segs x 1024 j; tile = 64 rows;
//     grid (64,8) = 512 blocks. Row-amortization unchanged (64 rows/wave).
//   * __launch_bounds__(256,3): cap 170 regs. acc 64 AGPR + ~105 arch VGPR
//     leaves room for FULL one-iter-ahead prefetch: ev/fv/b[4] (global) and
//     the 4 mask dwords (LDS). Each iter issues next-iter loads, computes
//     current entirely from regs -> latency hidden by ~350cyc compute.
//   * 3 blocks/CU (LDS 35 KB -> cap 4; regs -> 3) = 3 waves/SIMD, staggered
//     t-start (seg*8) so vmem bursts interleave. setprio kept (attn +, m191).
//   * reduction: 4 partials, 2 bufs, 4 syncs (tree halved vs v1).
// Mask from maskp (ws or in-place), chunk stride parametrized.
// Predicted: VGPR ~100-110 no scratch, dur 51 -> 26-34 µs.
// ---------------------------------------------------------------------------
__global__ __launch_bounds__(256, 3) void k_flash(
    const unsigned* __restrict__ maskp, int mstride,
    const float* __restrict__ srcv,
    const unsigned short* __restrict__ Ebf,
    const unsigned short* __restrict__ Fbf,
    const unsigned short* __restrict__ WhT,
    float* __restrict__ out) {
    __shared__ float st[2][64 * 68];     // 34816 B; mask (33792 B) aliases st
    __shared__ float lds_l[2][64];

    unsigned* lmask = (unsigned*)&st[0][0];   // [64 rows][132 dwords]

    const int tid   = threadIdx.x;
    const int seg   = tid >> 6;               // 0..3, 1024 j each
    const int lane  = tid & 63;
    const int row16 = lane & 15;
    const int quad  = lane >> 4;
    const int shl   = quad * 8;
    const int tile  = blockIdx.x;             // 64 rows
    const int h     = blockIdx.y;

    // ---- stage mask bits for 64 rows (32 row-pair chunks, 1 KB each)
#pragma unroll
    for (int p = 0; p < 8; ++p) {
        int tt = tid + p * 256;
        int c  = tt >> 6;                     // chunk 0..31
        int o  = (tt & 63) * 16;              // byte offset in chunk
        int4 v = *(const int4*)((const char*)maskp
                                + ((size_t)(tile * 32 + c) * mstride) * 4 + o);
        int row = c * 2 + (o >> 9);
        int dw  = (o & 511) >> 2;
        *(int4*)&lmask[row * 132 + dw] = v;
    }
    __syncthreads();

    // per-row src factors, packed f16x2 (both halves equal)
    f16x2 Es2[4], Fs2[4];
#pragma unroll
    for (int g = 0; g < 4; ++g) {
        float si = srcv[h * NN + tile * 64 + g * 16 + row16];
        _Float16 e = (_Float16)__expf(si);
        _Float16 f = (_Float16)__expf(ALPHA * si);
        Es2[g][0] = e; Es2[g][1] = e;
        Fs2[g][0] = f; Fs2[g][1] = f;
    }
    const int mbase = row16 * 132 + seg * 32;   // + g*2112 + t

    const unsigned short* Eb = Ebf + h * NN + seg * 1024;
    const unsigned short* Fb = Fbf + h * NN + seg * 1024;
    const unsigned short* wh = WhT + (size_t)h * FOUT * NN + seg * 1024;

    f32x4 acc[4][4] = {};
    float lsum[4]   = {};
    const f16x2 ones2 = {(_Float16)1.0f, (_Float16)1.0f};

    // rotated start + full one-iter-ahead prefetch
    int t = (seg * 8) & 31;
    union { f16x8 v8; f16x2 h2[4]; } evu, fvu;
    f16x8 bc[4];
    unsigned mc[4];
    {
        const int jj = t * 32 + shl;
        evu.v8 = *(const f16x8*)(Eb + jj);
        fvu.v8 = *(const f16x8*)(Fb + jj);
#pragma unroll
        for (int ot = 0; ot < 4; ++ot)
            bc[ot] = *(const f16x8*)(wh + (size_t)(ot * 16 + row16) * NN + jj);
#pragma unroll
        for (int g = 0; g < 4; ++g)
            mc[g] = lmask[mbase + g * 2112 + t];
    }

#pragma unroll 1
    for (int i = 0; i < 32; ++i) {
        const int tn = (t + 1) & 31;
        const int jn = tn * 32 + shl;
        // issue next iter's loads first (oldest in queues)
        union { f16x8 v8; f16x2 h2[4]; } evn, fvn;
        evn.v8 = *(const f16x8*)(Eb + jn);
        fvn.v8 = *(const f16x8*)(Fb + jn);
        f16x8 bn[4];
#pragma unroll
        for (int ot = 0; ot < 4; ++ot)
            bn[ot] = *(const f16x8*)(wh + (size_t)(ot * 16 + row16) * NN + jn);
        unsigned mn[4];
#pragma unroll
        for (int g = 0; g < 4; ++g)
            mn[g] = lmask[mbase + g * 2112 + tn];

        // compute current iter entirely from registers
#pragma unroll
        for (int g = 0; g < 4; ++g) {
            unsigned mb = mc[g] >> shl;   // bits 0..7
            union { f16x8 v8; unsigned w[4]; } au;
#pragma unroll
            for (int kk = 0; kk < 4; ++kk) {
                f16x2 t0 = evu.h2[kk] * Es2[g];
                f16x2 t1 = fvu.h2[kk] * Fs2[g];
                f16x2 p2 = __builtin_elementwise_max(t0, t1);
                unsigned lo = (unsigned)__builtin_amdgcn_sbfe((int)mb, 2 * kk, 1);
                unsigned hi = (unsigned)__builtin_amdgcn_sbfe((int)mb, 2 * kk + 1, 1);
                unsigned w  = (lo & 0xFFFFu) | (hi & 0xFFFF0000u);
                unsigned pw = __builtin_bit_cast(unsigned, p2) & w;
                f16x2 mp2   = __builtin_bit_cast(f16x2, pw);
                au.w[kk] = pw;
#if __has_builtin(__builtin_amdgcn_fdot2)
                lsum[g] = __builtin_amdgcn_fdot2(mp2, ones2, lsum[g], false);
#else
                lsum[g] += (float)mp2[0] + (float)mp2[1];
#endif
            }
            __builtin_amdgcn_s_setprio(1);
#pragma unroll
            for (int ot = 0; ot < 4; ++ot)
                acc[g][ot] = __builtin_amdgcn_mfma_f32_16x16x32_f16(au.v8, bc[ot], acc[g][ot], 0, 0, 0);
            __builtin_amdgcn_s_setprio(0);
        }
        evu.v8 = evn.v8;
        fvu.v8 = fvn.v8;
#pragma unroll
        for (int ot = 0; ot < 4; ++ot) bc[ot] = bn[ot];
#pragma unroll
        for (int g = 0; g < 4; ++g) mc[g] = mn[g];
        t = tn;
    }

    // complete per-row sums across the 4 quads (disjoint k coverage)
#pragma unroll
    for (int g = 0; g < 4; ++g) {
        lsum[g] += __shfl_xor(lsum[g], 16);
        lsum[g] += __shfl_xor(lsum[g], 32);
    }

    __syncthreads();   // mask reads done; st[] may be reused as stash

    auto stash = [&](int buf) {
#pragma unroll
        for (int g = 0; g < 4; ++g)
#pragma unroll
            for (int ot = 0; ot < 4; ++ot)
#pragma unroll
                for (int r = 0; r < 4; ++r)
                    st[buf][(g * 16 + quad * 4 + r) * 68 + ot * 16 + row16] = acc[g][ot][r];
        if (quad == 0)
#pragma unroll
            for (int g = 0; g < 4; ++g)
                lds_l[buf][g * 16 + row16] = lsum[g];
    };
    auto addin = [&](int buf) {
#pragma unroll
        for (int g = 0; g < 4; ++g) {
#pragma unroll
            for (int ot = 0; ot < 4; ++ot)
#pragma unroll
                for (int r = 0; r < 4; ++r)
                    acc[g][ot][r] += st[buf][(g * 16 + quad * 4 + r) * 68 + ot * 16 + row16];
            lsum[g] += lds_l[buf][g * 16 + row16];
        }
    };

    if (seg == 1) stash(0);
    if (seg == 3) stash(1);
    __syncthreads();
    if (seg == 0) addin(0);
    if (seg == 2) addin(1);
    __syncthreads();
    if (seg == 2) stash(0);
    __syncthreads();
    if (seg == 0) {
        addin(0);
        // epilogue: divide by l, ELU, deposit final 64x64 tile into st[0]
#pragma unroll
        for (int g = 0; g < 4; ++g)
#pragma unroll
            for (int r = 0; r < 4; ++r) {
                int   qr  = quad * 4 + r;
                float l   = __shfl(lsum[g], qr);    // lane qr holds row qr's sum
                float rl  = 1.0f / l;
#pragma unroll
                for (int ot = 0; ot < 4; ++ot) {
                    float v = acc[g][ot][r] * rl;
                    float y = v > 0.f ? v : __expf(v) - 1.f;
                    st[0][(g * 16 + qr) * 68 + ot * 16 + row16] = y;
                }
            }
    }
    __syncthreads();
    // cooperative coalesced store: 1024 float4s by 256 threads
#pragma unroll
    for (int p = 0; p < 4; ++p) {
        int f    = tid + p * 256;
        int row  = f >> 4;
        int col4 = (f & 15) * 4;
        float4 v = *(const float4*)&st[0][row * 68 + col4];
        *(float4*)&out[(size_t)(tile * 64 + row) * (HH * FOUT) + h * FOUT + col4] = v;
    }
}

// ---------------------------------------------------------------------------
extern "C" void kernel_launch(void* const* d_in, const int* in_sizes, int n_in,
                              void* d_out, int out_size, void* d_ws, size_t ws_size,
                              hipStream_t stream) {
    const float* features = (const float*)d_in[0];
    int*         adj      = (int*)d_in[1];
    const float* W        = (const float*)d_in[2];
    const float* a_src    = (const float*)d_in[3];
    const float* a_dst    = (const float*)d_in[4];
    float*       out      = (float*)d_out;

    char* ws = (char*)d_ws;
    __hip_bfloat16* WT   = (__hip_bfloat16*)(ws);                             // 512 KB
    unsigned short* WhT  = (unsigned short*)(ws + (512 << 10));               // 4 MB (f16)
    float*          srcv = (float*)(ws + (512 << 10) + (4 << 20));            // 128 KB
    unsigned short* Ebf  = (unsigned short*)(ws + (512 << 10) + (4 << 20) + (128 << 10));  // 64 KB (f16)
    unsigned short* Fbf  = (unsigned short*)(ws + (512 << 10) + (4 << 20) + (192 << 10));  // 64 KB (f16)

    // packed mask: 2 MB in ws if it fits (keeps adj read-only -> no harness
    // restore of 64 MB input per iter); else fall back to in-place layout.
    const size_t mask_off = (512 << 10) + (4 << 20) + (256 << 10);            // 4.75 MB
    unsigned* maskp; int mstride;
    if (ws_size >= mask_off + (2u << 20)) {
        maskp   = (unsigned*)(ws + mask_off);
        mstride = 256;                         // contiguous: 256 dwords / row-pair
    } else {
        maskp   = (unsigned*)adj;              // in-place fallback (old layout)
        mstride = 8192;
    }

    k_transpose_w<<<dim3(64), 256, 0, stream>>>(W, WT);
    k_prep<<<dim3(2048 + 256), 256, 0, stream>>>(adj, maskp, mstride,
                                                 features, WT, a_src, a_dst,
                                                 WhT, srcv, Ebf, Fbf);
    k_flash<<<dim3(64, 8), 256, 0, stream>>>(maskp, mstride, srcv, Ebf, Fbf,
                                             WhT, out);
}

// Round 5
// 153.944 us; speedup vs baseline: 1.2615x; 1.0683x over previous
//
#include <hip/hip_runtime.h>
#include <hip/hip_bf16.h>

typedef __bf16 bf16x8 __attribute__((ext_vector_type(8)));
typedef _Float16 f16x8 __attribute__((ext_vector_type(8)));
typedef _Float16 f16x2 __attribute__((ext_vector_type(2)));
typedef float  f32x4  __attribute__((ext_vector_type(4)));
typedef unsigned short u16x8 __attribute__((ext_vector_type(8)));
typedef unsigned short us4   __attribute__((ext_vector_type(4)));

#define HH    8
#define NN    4096
#define FIN   512
#define FOUT  64
#define ALPHA 0.2f

// ---------------------------------------------------------------------------
// k0: W[h][f][o] (fp32) -> WT[h][o][f] (bf16), coalesced via LDS 64x64 tile.
// ---------------------------------------------------------------------------
__global__ __launch_bounds__(256) void k_transpose_w(
    const float* __restrict__ Wsrc, __hip_bfloat16* __restrict__ WT) {
    __shared__ __hip_bfloat16 lt[64][65];
    const int h  = blockIdx.x >> 3;
    const int f0 = (blockIdx.x & 7) * 64;
    const int tid = threadIdx.x;
#pragma unroll
    for (int p = 0; p < 16; ++p) {
        int f = p * 4 + (tid >> 6);
        int o = tid & 63;
        lt[f][o] = __float2bfloat16(Wsrc[((size_t)h * FIN + f0 + f) * FOUT + o]);
    }
    __syncthreads();
#pragma unroll
    for (int p = 0; p < 16; ++p) {
        int o = p * 4 + (tid >> 6);
        int f = tid & 63;
        WT[((size_t)h * FOUT + o) * FIN + f0 + f] = lt[f][o];
    }
}

// ---------------------------------------------------------------------------
// k_prep: FUSED adjacency bit-pack + projection.
// R16 change: WhT is stored TILED: [h][jb][o][jm] with jb=j/32, jm=j%32
// (4-KB contiguous tile per (h, 32-j-block)). Rationale: the old [h][o][j]
// layout made every k_flash b-load a 16-segment gather (rows 8 KB apart,
// 64 B per row) -> ~64 memory transactions per iter per wave -> the TA pipe,
// not bytes, was the k_flash bottleneck across ALL previous rounds. The us4
// projection store stays within one 32-j tile (n-window = 32), so the write
// is just re-addressed, not restructured.
// Blocks [0,2048): pack adj bits into ws (adj stays read-only).
// Blocks [2048,2304): projection (f16 WhT/Ebf/Fbf outputs).
// ---------------------------------------------------------------------------
__global__ __launch_bounds__(256) void k_prep(
    const int* __restrict__ adj,
    unsigned* __restrict__ maskdst, int mstride,
    const float* __restrict__ feat,
    const __hip_bfloat16* __restrict__ WT,
    const float* __restrict__ a_src,
    const float* __restrict__ a_dst,
    unsigned short* __restrict__ WhT,
    float* __restrict__ srcv,
    unsigned short* __restrict__ Ebf, unsigned short* __restrict__ Fbf) {
    __shared__ alignas(16) __hip_bfloat16 lfeat[32][520];

    const int tid = threadIdx.x;

    if (blockIdx.x < 2048) {   // ---- pack path ----
        const size_t base = (size_t)blockIdx.x * 8192;
        unsigned m = 0;
#pragma unroll
        for (int p = 0; p < 8; ++p) {
            int4 v = *(const int4*)(adj + base + tid * 32 + p * 4);
            m |= (unsigned)(v.x > 0) << (p * 4);
            m |= (unsigned)(v.y > 0) << (p * 4 + 1);
            m |= (unsigned)(v.z > 0) << (p * 4 + 2);
            m |= (unsigned)(v.w > 0) << (p * 4 + 3);
        }
        __syncthreads();   // needed only for in-place fallback; cheap
        maskdst[(size_t)blockIdx.x * mstride + tid] = m;
        return;
    }

    // ---- projection path ----
    const int pb   = blockIdx.x - 2048;
    const int tile = pb & 127;            // 32 rows per block
    const int hgy  = pb >> 7;             // 0..1

#pragma unroll
    for (int p = 0; p < 16; ++p) {
        int idx  = p * 256 + tid;
        int row  = idx >> 7;
        int col4 = (idx & 127) * 4;
        float4 f = *(const float4*)(feat + (size_t)(tile * 32 + row) * FIN + col4);
        __hip_bfloat16* dst = &lfeat[row][col4];
        dst[0] = __float2bfloat16(f.x); dst[1] = __float2bfloat16(f.y);
        dst[2] = __float2bfloat16(f.z); dst[3] = __float2bfloat16(f.w);
    }
    __syncthreads();

    const int h     = hgy * 4 + (tid >> 6);
    const int lane  = tid & 63;
    const int row16 = lane & 15;
    const int quad  = lane >> 4;

    const unsigned short* WTu = (const unsigned short*)WT + (size_t)h * FOUT * FIN;

    f32x4 acc[2][4] = {};
    for (int k0 = 0; k0 < FIN; k0 += 32) {
        bf16x8 a0 = *(const bf16x8*)&lfeat[row16][k0 + quad * 8];
        bf16x8 a1 = *(const bf16x8*)&lfeat[16 + row16][k0 + quad * 8];
#pragma unroll
        for (int ot = 0; ot < 4; ++ot) {
            bf16x8 b = *(const bf16x8*)(WTu + (size_t)(ot * 16 + row16) * FIN + k0 + quad * 8);
            acc[0][ot] = __builtin_amdgcn_mfma_f32_16x16x32_bf16(a0, b, acc[0][ot], 0, 0, 0);
            acc[1][ot] = __builtin_amdgcn_mfma_f32_16x16x32_bf16(a1, b, acc[1][ot], 0, 0, 0);
        }
    }

    // tiled WhT store: [h][jb=tile][o][jm], jm = g*16 + quad*4 + r
#pragma unroll
    for (int g = 0; g < 2; ++g)
#pragma unroll
        for (int ot = 0; ot < 4; ++ot) {
            us4 u;
#pragma unroll
            for (int r = 0; r < 4; ++r)
                u[r] = __builtin_bit_cast(unsigned short, (_Float16)acc[g][ot][r]);
            *(us4*)(WhT + (((size_t)(h * 128 + tile) * 64 + ot * 16 + row16) << 5)
                        + g * 16 + quad * 4) = u;
        }

    float asv[4], adv[4];
#pragma unroll
    for (int ot = 0; ot < 4; ++ot) {
        asv[ot] = a_src[h * FOUT + ot * 16 + row16];
        adv[ot] = a_dst[h * FOUT + ot * 16 + row16];
    }
#pragma unroll
    for (int g = 0; g < 2; ++g)
#pragma unroll
        for (int r = 0; r < 4; ++r) {
            float ss = 0.f, dd = 0.f;
#pragma unroll
            for (int ot = 0; ot < 4; ++ot) {
                ss += acc[g][ot][r] * asv[ot];
                dd += acc[g][ot][r] * adv[ot];
            }
            ss += __shfl_xor(ss, 1); ss += __shfl_xor(ss, 2);
            ss += __shfl_xor(ss, 4); ss += __shfl_xor(ss, 8);
            dd += __shfl_xor(dd, 1); dd += __shfl_xor(dd, 2);
            dd += __shfl_xor(dd, 4); dd += __shfl_xor(dd, 8);
            if (row16 == 0) {
                int n = tile * 32 + g * 16 + quad * 4 + r;
                srcv[h * NN + n] = ss;
                _Float16 e = (_Float16)__expf(dd);
                _Float16 f = (_Float16)__expf(ALPHA * dd);
                Ebf[h * NN + n] = __builtin_bit_cast(unsigned short, e);
                Fbf[h * NN + n] = __builtin_bit_cast(unsigned short, f);
            }
        }
}

// ---------------------------------------------------------------------------
// k_flash v6: packed-f16 masked softmax attention + ELU, COALESCED b-loads.
// R16 theory: v5's 47 µs vs ~12-15 µs pipe demand was the [o][j] WhT layout:
// each b-load gathered 16 scattered 64-B segments (rows 8 KB apart) -> 16
// transactions/inst, ~64/iter/wave -> address-pipe bound. With tiled WhT
// ([h][jb][o][32j], 4-KB tiles) a b-load's 64 lanes cover ONE contiguous
// 1 KB span -> 1-2 transactions. Also:
//   * ping-pong 2x-unrolled prefetch (A/B reg sets) — kills the ~28
//     v_mov/iter rotation copies of v5;
//   * t-stagger now includes block parity ((tile&1)<<2) so the two
//     co-resident same-seg waves (different blocks) desync their vmem bursts.
// Structure unchanged: 256 thr = 4 waves = 4 j-segs x 1024 j; 64-row tile;
// grid (64,8) = 512 blocks (2/CU, grid-capped); acc[4][4]=64 AGPR.
// Predicted: dur 47 -> 20-27 µs. If >38: transaction theory wrong -> TA/L1
// counters or LDS-stage WhT next.
// ---------------------------------------------------------------------------
__global__ __launch_bounds__(256, 3) void k_flash(
    const unsigned* __restrict__ maskp, int mstride,
    const float* __restrict__ srcv,
    const unsigned short* __restrict__ Ebf,
    const unsigned short* __restrict__ Fbf,
    const unsigned short* __restrict__ WhT,
    float* __restrict__ out) {
    __shared__ float st[2][64 * 68];     // 34816 B; mask (33792 B) aliases st
    __shared__ float lds_l[2][64];

    unsigned* lmask = (unsigned*)&st[0][0];   // [64 rows][132 dwords]

    const int tid   = threadIdx.x;
    const int seg   = tid >> 6;               // 0..3, 1024 j each
    const int lane  = tid & 63;
    const int row16 = lane & 15;
    const int quad  = lane >> 4;
    const int shl   = quad * 8;
    const int tile  = blockIdx.x;             // 64 rows
    const int h     = blockIdx.y;

    // ---- stage mask bits for 64 rows (32 row-pair chunks, 1 KB each)
#pragma unroll
    for (int p = 0; p < 8; ++p) {
        int tt = tid + p * 256;
        int c  = tt >> 6;                     // chunk 0..31
        int o  = (tt & 63) * 16;              // byte offset in chunk
        int4 v = *(const int4*)((const char*)maskp
                                + ((size_t)(tile * 32 + c) * mstride) * 4 + o);
        int row = c * 2 + (o >> 9);
        int dw  = (o & 511) >> 2;
        *(int4*)&lmask[row * 132 + dw] = v;
    }
    __syncthreads();

    // per-row src factors, packed f16x2 (both halves equal)
    f16x2 Es2[4], Fs2[4];
#pragma unroll
    for (int g = 0; g < 4; ++g) {
        float si = srcv[h * NN + tile * 64 + g * 16 + row16];
        _Float16 e = (_Float16)__expf(si);
        _Float16 f = (_Float16)__expf(ALPHA * si);
        Es2[g][0] = e; Es2[g][1] = e;
        Fs2[g][0] = f; Fs2[g][1] = f;
    }
    const int mbase = row16 * 132 + seg * 32;   // + g*2112 + t

    const unsigned short* Eb  = Ebf + h * NN + seg * 1024;
    const unsigned short* Fb  = Fbf + h * NN + seg * 1024;
    const unsigned short* whh = WhT + (size_t)h * FOUT * NN;   // tiled base

    f32x4 acc[4][4] = {};
    float lsum[4]   = {};
    const f16x2 ones2 = {(_Float16)1.0f, (_Float16)1.0f};

    auto LOAD = [&](f16x8& ev_, f16x8& fv_, f16x8* b_, unsigned* m_, int tt) {
        const int jj = tt * 32 + shl;
        const size_t jb = (size_t)(seg * 32 + tt) << 11;   // tile offset (2048 el)
        ev_ = *(const f16x8*)(Eb + jj);
        fv_ = *(const f16x8*)(Fb + jj);
#pragma unroll
        for (int ot = 0; ot < 4; ++ot)
            b_[ot] = *(const f16x8*)(whh + jb + (ot * 16 + row16) * 32 + quad * 8);
#pragma unroll
        for (int g = 0; g < 4; ++g)
            m_[g] = lmask[mbase + g * 2112 + tt];
    };

    auto COMP = [&](const f16x8& ev_, const f16x8& fv_,
                    const f16x8* b_, const unsigned* m_) {
        union { f16x8 v8; f16x2 h2[4]; } evu, fvu;
        evu.v8 = ev_; fvu.v8 = fv_;
#pragma unroll
        for (int g = 0; g < 4; ++g) {
            unsigned mb = m_[g] >> shl;   // bits 0..7
            union { f16x8 v8; unsigned w[4]; } au;
#pragma unroll
            for (int kk = 0; kk < 4; ++kk) {
                f16x2 t0 = evu.h2[kk] * Es2[g];
                f16x2 t1 = fvu.h2[kk] * Fs2[g];
                f16x2 p2 = __builtin_elementwise_max(t0, t1);
                unsigned lo = (unsigned)__builtin_amdgcn_sbfe((int)mb, 2 * kk, 1);
                unsigned hi = (unsigned)__builtin_amdgcn_sbfe((int)mb, 2 * kk + 1, 1);
                unsigned w  = (lo & 0xFFFFu) | (hi & 0xFFFF0000u);
                unsigned pw = __builtin_bit_cast(unsigned, p2) & w;
                f16x2 mp2   = __builtin_bit_cast(f16x2, pw);
                au.w[kk] = pw;
#if __has_builtin(__builtin_amdgcn_fdot2)
                lsum[g] = __builtin_amdgcn_fdot2(mp2, ones2, lsum[g], false);
#else
                lsum[g] += (float)mp2[0] + (float)mp2[1];
#endif
            }
            __builtin_amdgcn_s_setprio(1);
#pragma unroll
            for (int ot = 0; ot < 4; ++ot)
                acc[g][ot] = __builtin_amdgcn_mfma_f32_16x16x32_f16(au.v8, b_[ot], acc[g][ot], 0, 0, 0);
            __builtin_amdgcn_s_setprio(0);
        }
    };

    // stagger: seg phase + block parity (co-resident waves have same seg)
    int t0 = ((seg * 8) + ((tile & 1) << 2)) & 31;
    f16x8 evA, fvA, bA[4]; unsigned mA[4];
    f16x8 evB, fvB, bB[4]; unsigned mB[4];
    LOAD(evA, fvA, bA, mA, t0);

#pragma unroll 1
    for (int i = 0; i < 16; ++i) {
        const int t1 = (t0 + 1) & 31;
        LOAD(evB, fvB, bB, mB, t1);
        COMP(evA, fvA, bA, mA);
        const int t2 = (t0 + 2) & 31;
        LOAD(evA, fvA, bA, mA, t2);     // last one (i=15) is redundant, harmless
        COMP(evB, fvB, bB, mB);
        t0 = t2;
    }

    // complete per-row sums across the 4 quads (disjoint k coverage)
#pragma unroll
    for (int g = 0; g < 4; ++g) {
        lsum[g] += __shfl_xor(lsum[g], 16);
        lsum[g] += __shfl_xor(lsum[g], 32);
    }

    __syncthreads();   // mask reads done; st[] may be reused as stash

    auto stash = [&](int buf) {
#pragma unroll
        for (int g = 0; g < 4; ++g)
#pragma unroll
            for (int ot = 0; ot < 4; ++ot)
#pragma unroll
                for (int r = 0; r < 4; ++r)
                    st[buf][(g * 16 + quad * 4 + r) * 68 + ot * 16 + row16] = acc[g][ot][r];
        if (quad == 0)
#pragma unroll
            for (int g = 0; g < 4; ++g)
                lds_l[buf][g * 16 + row16] = lsum[g];
    };
    auto addin = [&](int buf) {
#pragma unroll
        for (int g = 0; g < 4; ++g) {
#pragma unroll
            for (int ot = 0; ot < 4; ++ot)
#pragma unroll
                for (int r = 0; r < 4; ++r)
                    acc[g][ot][r] += st[buf][(g * 16 + quad * 4 + r) * 68 + ot * 16 + row16];
            lsum[g] += lds_l[buf][g * 16 + row16];
        }
    };

    if (seg == 1) stash(0);
    if (seg == 3) stash(1);
    __syncthreads();
    if (seg == 0) addin(0);
    if (seg == 2) addin(1);
    __syncthreads();
    if (seg == 2) stash(0);
    __syncthreads();
    if (seg == 0) {
        addin(0);
        // epilogue: divide by l, ELU, deposit final 64x64 tile into st[0]
#pragma unroll
        for (int g = 0; g < 4; ++g)
#pragma unroll
            for (int r = 0; r < 4; ++r) {
                int   qr  = quad * 4 + r;
                float l   = __shfl(lsum[g], qr);    // lane qr holds row qr's sum
                float rl  = 1.0f / l;
#pragma unroll
                for (int ot = 0; ot < 4; ++ot) {
                    float v = acc[g][ot][r] * rl;
                    float y = v > 0.f ? v : __expf(v) - 1.f;
                    st[0][(g * 16 + qr) * 68 + ot * 16 + row16] = y;
                }
            }
    }
    __syncthreads();
    // cooperative coalesced store: 1024 float4s by 256 threads
#pragma unroll
    for (int p = 0; p < 4; ++p) {
        int f    = tid + p * 256;
        int row  = f >> 4;
        int col4 = (f & 15) * 4;
        float4 v = *(const float4*)&st[0][row * 68 + col4];
        *(float4*)&out[(size_t)(tile * 64 + row) * (HH * FOUT) + h * FOUT + col4] = v;
    }
}

// ---------------------------------------------------------------------------
extern "C" void kernel_launch(void* const* d_in, const int* in_sizes, int n_in,
                              void* d_out, int out_size, void* d_ws, size_t ws_size,
                              hipStream_t stream) {
    const float* features = (const float*)d_in[0];
    int*         adj      = (int*)d_in[1];
    const float* W        = (const float*)d_in[2];
    const float* a_src    = (const float*)d_in[3];
    const float* a_dst    = (const float*)d_in[4];
    float*       out      = (float*)d_out;

    char* ws = (char*)d_ws;
    __hip_bfloat16* WT   = (__hip_bfloat16*)(ws);                             // 512 KB
    unsigned short* WhT  = (unsigned short*)(ws + (512 << 10));               // 4 MB (f16, tiled)
    float*          srcv = (float*)(ws + (512 << 10) + (4 << 20));            // 128 KB
    unsigned short* Ebf  = (unsigned short*)(ws + (512 << 10) + (4 << 20) + (128 << 10));  // 64 KB (f16)
    unsigned short* Fbf  = (unsigned short*)(ws + (512 << 10) + (4 << 20) + (192 << 10));  // 64 KB (f16)

    // packed mask: 2 MB in ws if it fits (keeps adj read-only); else in-place.
    const size_t mask_off = (512 << 10) + (4 << 20) + (256 << 10);            // 4.75 MB
    unsigned* maskp; int mstride;
    if (ws_size >= mask_off + (2u << 20)) {
        maskp   = (unsigned*)(ws + mask_off);
        mstride = 256;                         // contiguous: 256 dwords / row-pair
    } else {
        maskp   = (unsigned*)adj;              // in-place fallback (old layout)
        mstride = 8192;
    }

    k_transpose_w<<<dim3(64), 256, 0, stream>>>(W, WT);
    k_prep<<<dim3(2048 + 256), 256, 0, stream>>>(adj, maskp, mstride,
                                                 features, WT, a_src, a_dst,
                                                 WhT, srcv, Ebf, Fbf);
    k_flash<<<dim3(64, 8), 256, 0, stream>>>(maskp, mstride, srcv, Ebf, Fbf,
                                             WhT, out);
}

// Round 6
// 143.288 us; speedup vs baseline: 1.3553x; 1.0744x over previous
//
#include <hip/hip_runtime.h>
#include <hip/hip_bf16.h>

typedef __bf16 bf16x8 __attribute__((ext_vector_type(8)));
typedef _Float16 f16x8 __attribute__((ext_vector_type(8)));
typedef _Float16 f16x2 __attribute__((ext_vector_type(2)));
typedef float  f32x4  __attribute__((ext_vector_type(4)));
typedef unsigned short u16x8 __attribute__((ext_vector_type(8)));
typedef unsigned short us4   __attribute__((ext_vector_type(4)));

#define HH    8
#define NN    4096
#define FIN   512
#define FOUT  64
#define ALPHA 0.2f

// ---------------------------------------------------------------------------
// k0: W[h][f][o] (fp32) -> WT2 TILED bf16: [h][kb][o][km], f = kb*32+km.
// R17: tiled so k_prep's b-loads are contiguous-1KB per instruction (the
// old [h][o][f] layout made them 16-segment gathers, rows 1 KB apart).
// ---------------------------------------------------------------------------
__global__ __launch_bounds__(256) void k_transpose_w(
    const float* __restrict__ Wsrc, __hip_bfloat16* __restrict__ WT) {
    __shared__ __hip_bfloat16 lt[64][65];
    const int h  = blockIdx.x >> 3;
    const int f0 = (blockIdx.x & 7) * 64;
    const int tid = threadIdx.x;
#pragma unroll
    for (int p = 0; p < 16; ++p) {
        int f = p * 4 + (tid >> 6);
        int o = tid & 63;
        lt[f][o] = __float2bfloat16(Wsrc[((size_t)h * FIN + f0 + f) * FOUT + o]);
    }
    __syncthreads();
#pragma unroll
    for (int p = 0; p < 16; ++p) {
        int o = p * 4 + (tid >> 6);
        int f = tid & 63;          // local f; global f = f0 + f
        int gf = f0 + f;
        // WT2[h][kb][o][km]: ((h*16 + gf/32)*64 + o)*32 + gf%32
        WT[(((size_t)h * 16 + (gf >> 5)) * 64 + o) * 32 + (gf & 31)] = lt[f][o];
    }
}

// ---------------------------------------------------------------------------
// k_prep: FUSED adjacency bit-pack + projection.
// R17 changes (k_prep was 42 µs with all pipes <15% — transaction-bound):
//  * pack path: lane-CONTIGUOUS int4 loads (wave = 4 KB contiguous, 16
//    transactions vs 64 for the old 128-B-stride pattern). Bits assembled
//    cross-lane: nibble -> shift -> 3x shfl_xor OR-tree (8-lane groups) ->
//    rotating keep -> LDS scatter (1 KB) -> coalesced global write.
//    Layout identical to before: dword d of block b covers cols 32d..32d+31
//    of the row-pair (2b, 2b+1).
//  * projection b-loads read the TILED WT2 (contiguous 1 KB per inst).
//  * projection blocks dispatched FIRST (blockIdx < 256) to overlap pack
//    instead of trailing it serially.
// ---------------------------------------------------------------------------
__global__ __launch_bounds__(256) void k_prep(
    const int* __restrict__ adj,
    unsigned* __restrict__ maskdst, int mstride,
    const float* __restrict__ feat,
    const __hip_bfloat16* __restrict__ WT,
    const float* __restrict__ a_src,
    const float* __restrict__ a_dst,
    unsigned short* __restrict__ WhT,
    float* __restrict__ srcv,
    unsigned short* __restrict__ Ebf, unsigned short* __restrict__ Fbf) {
    __shared__ alignas(16) __hip_bfloat16 lfeat[32][520];

    const int tid = threadIdx.x;

    if (blockIdx.x >= 256) {   // ---- pack path ----
        const int b = blockIdx.x - 256;
        const size_t base = (size_t)b * 8192;
        unsigned* lbuf = (unsigned*)&lfeat[0][0];    // 1 KB alias
        const int l = tid & 63;
        const int w = tid >> 6;
        unsigned keep = 0;
#pragma unroll
        for (int i = 0; i < 8; ++i) {
            int4 v = *(const int4*)(adj + base + (size_t)(i * 256 + tid) * 4);
            unsigned nib = (unsigned)(v.x > 0) | ((unsigned)(v.y > 0) << 1)
                         | ((unsigned)(v.z > 0) << 2) | ((unsigned)(v.w > 0) << 3);
            unsigned vv = nib << ((l & 7) * 4);
            vv |= __shfl_xor(vv, 1);
            vv |= __shfl_xor(vv, 2);
            vv |= __shfl_xor(vv, 4);
            keep = ((l & 7) == i) ? vv : keep;
        }
        // lane l holds dword (i = l&7, d = l>>3): index = (l&7)*32 + w*8 + (l>>3)
        lbuf[(l & 7) * 32 + w * 8 + (l >> 3)] = keep;
        __syncthreads();
        maskdst[(size_t)b * mstride + tid] = lbuf[tid];
        return;
    }

    // ---- projection path ----
    const int pb   = blockIdx.x;
    const int tile = pb & 127;            // 32 rows per block
    const int hgy  = pb >> 7;             // 0..1

#pragma unroll
    for (int p = 0; p < 16; ++p) {
        int idx  = p * 256 + tid;
        int row  = idx >> 7;
        int col4 = (idx & 127) * 4;
        float4 f = *(const float4*)(feat + (size_t)(tile * 32 + row) * FIN + col4);
        __hip_bfloat16* dst = &lfeat[row][col4];
        dst[0] = __float2bfloat16(f.x); dst[1] = __float2bfloat16(f.y);
        dst[2] = __float2bfloat16(f.z); dst[3] = __float2bfloat16(f.w);
    }
    __syncthreads();

    const int h     = hgy * 4 + (tid >> 6);
    const int lane  = tid & 63;
    const int row16 = lane & 15;
    const int quad  = lane >> 4;

    // tiled WT2 base for head h: 16 kb-tiles x 2048 elements
    const unsigned short* WTu = (const unsigned short*)WT + (size_t)h * 16 * 2048;

    f32x4 acc[2][4] = {};
    for (int k0 = 0; k0 < FIN; k0 += 32) {
        bf16x8 a0 = *(const bf16x8*)&lfeat[row16][k0 + quad * 8];
        bf16x8 a1 = *(const bf16x8*)&lfeat[16 + row16][k0 + quad * 8];
        const unsigned short* wkb = WTu + (size_t)(k0 >> 5) * 2048;
#pragma unroll
        for (int ot = 0; ot < 4; ++ot) {
            bf16x8 b = *(const bf16x8*)(wkb + (ot * 16 + row16) * 32 + quad * 8);
            acc[0][ot] = __builtin_amdgcn_mfma_f32_16x16x32_bf16(a0, b, acc[0][ot], 0, 0, 0);
            acc[1][ot] = __builtin_amdgcn_mfma_f32_16x16x32_bf16(a1, b, acc[1][ot], 0, 0, 0);
        }
    }

    // tiled WhT store: [h][jb=tile][o][jm], jm = g*16 + quad*4 + r
#pragma unroll
    for (int g = 0; g < 2; ++g)
#pragma unroll
        for (int ot = 0; ot < 4; ++ot) {
            us4 u;
#pragma unroll
            for (int r = 0; r < 4; ++r)
                u[r] = __builtin_bit_cast(unsigned short, (_Float16)acc[g][ot][r]);
            *(us4*)(WhT + (((size_t)(h * 128 + tile) * 64 + ot * 16 + row16) << 5)
                        + g * 16 + quad * 4) = u;
        }

    float asv[4], adv[4];
#pragma unroll
    for (int ot = 0; ot < 4; ++ot) {
        asv[ot] = a_src[h * FOUT + ot * 16 + row16];
        adv[ot] = a_dst[h * FOUT + ot * 16 + row16];
    }
#pragma unroll
    for (int g = 0; g < 2; ++g)
#pragma unroll
        for (int r = 0; r < 4; ++r) {
            float ss = 0.f, dd = 0.f;
#pragma unroll
            for (int ot = 0; ot < 4; ++ot) {
                ss += acc[g][ot][r] * asv[ot];
                dd += acc[g][ot][r] * adv[ot];
            }
            ss += __shfl_xor(ss, 1); ss += __shfl_xor(ss, 2);
            ss += __shfl_xor(ss, 4); ss += __shfl_xor(ss, 8);
            dd += __shfl_xor(dd, 1); dd += __shfl_xor(dd, 2);
            dd += __shfl_xor(dd, 4); dd += __shfl_xor(dd, 8);
            if (row16 == 0) {
                int n = tile * 32 + g * 16 + quad * 4 + r;
                srcv[h * NN + n] = ss;
                _Float16 e = (_Float16)__expf(dd);
                _Float16 f = (_Float16)__expf(ALPHA * dd);
                Ebf[h * NN + n] = __builtin_bit_cast(unsigned short, e);
                Fbf[h * NN + n] = __builtin_bit_cast(unsigned short, f);
            }
        }
}

// ---------------------------------------------------------------------------
// k_flash v6 (unchanged from R16 — coalesced tiled-WhT b-loads, ping-pong
// prefetch, seg+parity stagger, setprio). R16 prediction confirmed: fell out
// of top-5 (<~30 µs, was 47).
// ---------------------------------------------------------------------------
__global__ __launch_bounds__(256, 3) void k_flash(
    const unsigned* __restrict__ maskp, int mstride,
    const float* __restrict__ srcv,
    const unsigned short* __restrict__ Ebf,
    const unsigned short* __restrict__ Fbf,
    const unsigned short* __restrict__ WhT,
    float* __restrict__ out) {
    __shared__ float st[2][64 * 68];     // 34816 B; mask (33792 B) aliases st
    __shared__ float lds_l[2][64];

    unsigned* lmask = (unsigned*)&st[0][0];   // [64 rows][132 dwords]

    const int tid   = threadIdx.x;
    const int seg   = tid >> 6;               // 0..3, 1024 j each
    const int lane  = tid & 63;
    const int row16 = lane & 15;
    const int quad  = lane >> 4;
    const int shl   = quad * 8;
    const int tile  = blockIdx.x;             // 64 rows
    const int h     = blockIdx.y;

    // ---- stage mask bits for 64 rows (32 row-pair chunks, 1 KB each)
#pragma unroll
    for (int p = 0; p < 8; ++p) {
        int tt = tid + p * 256;
        int c  = tt >> 6;                     // chunk 0..31
        int o  = (tt & 63) * 16;              // byte offset in chunk
        int4 v = *(const int4*)((const char*)maskp
                                + ((size_t)(tile * 32 + c) * mstride) * 4 + o);
        int row = c * 2 + (o >> 9);
        int dw  = (o & 511) >> 2;
        *(int4*)&lmask[row * 132 + dw] = v;
    }
    __syncthreads();

    // per-row src factors, packed f16x2 (both halves equal)
    f16x2 Es2[4], Fs2[4];
#pragma unroll
    for (int g = 0; g < 4; ++g) {
        float si = srcv[h * NN + tile * 64 + g * 16 + row16];
        _Float16 e = (_Float16)__expf(si);
        _Float16 f = (_Float16)__expf(ALPHA * si);
        Es2[g][0] = e; Es2[g][1] = e;
        Fs2[g][0] = f; Fs2[g][1] = f;
    }
    const int mbase = row16 * 132 + seg * 32;   // + g*2112 + t

    const unsigned short* Eb  = Ebf + h * NN + seg * 1024;
    const unsigned short* Fb  = Fbf + h * NN + seg * 1024;
    const unsigned short* whh = WhT + (size_t)h * FOUT * NN;   // tiled base

    f32x4 acc[4][4] = {};
    float lsum[4]   = {};
    const f16x2 ones2 = {(_Float16)1.0f, (_Float16)1.0f};

    auto LOAD = [&](f16x8& ev_, f16x8& fv_, f16x8* b_, unsigned* m_, int tt) {
        const int jj = tt * 32 + shl;
        const size_t jb = (size_t)(seg * 32 + tt) << 11;   // tile offset (2048 el)
        ev_ = *(const f16x8*)(Eb + jj);
        fv_ = *(const f16x8*)(Fb + jj);
#pragma unroll
        for (int ot = 0; ot < 4; ++ot)
            b_[ot] = *(const f16x8*)(whh + jb + (ot * 16 + row16) * 32 + quad * 8);
#pragma unroll
        for (int g = 0; g < 4; ++g)
            m_[g] = lmask[mbase + g * 2112 + tt];
    };

    auto COMP = [&](const f16x8& ev_, const f16x8& fv_,
                    const f16x8* b_, const unsigned* m_) {
        union { f16x8 v8; f16x2 h2[4]; } evu, fvu;
        evu.v8 = ev_; fvu.v8 = fv_;
#pragma unroll
        for (int g = 0; g < 4; ++g) {
            unsigned mb = m_[g] >> shl;   // bits 0..7
            union { f16x8 v8; unsigned w[4]; } au;
#pragma unroll
            for (int kk = 0; kk < 4; ++kk) {
                f16x2 t0 = evu.h2[kk] * Es2[g];
                f16x2 t1 = fvu.h2[kk] * Fs2[g];
                f16x2 p2 = __builtin_elementwise_max(t0, t1);
                unsigned lo = (unsigned)__builtin_amdgcn_sbfe((int)mb, 2 * kk, 1);
                unsigned hi = (unsigned)__builtin_amdgcn_sbfe((int)mb, 2 * kk + 1, 1);
                unsigned w  = (lo & 0xFFFFu) | (hi & 0xFFFF0000u);
                unsigned pw = __builtin_bit_cast(unsigned, p2) & w;
                f16x2 mp2   = __builtin_bit_cast(f16x2, pw);
                au.w[kk] = pw;
#if __has_builtin(__builtin_amdgcn_fdot2)
                lsum[g] = __builtin_amdgcn_fdot2(mp2, ones2, lsum[g], false);
#else
                lsum[g] += (float)mp2[0] + (float)mp2[1];
#endif
            }
            __builtin_amdgcn_s_setprio(1);
#pragma unroll
            for (int ot = 0; ot < 4; ++ot)
                acc[g][ot] = __builtin_amdgcn_mfma_f32_16x16x32_f16(au.v8, b_[ot], acc[g][ot], 0, 0, 0);
            __builtin_amdgcn_s_setprio(0);
        }
    };

    // stagger: seg phase + block parity (co-resident waves have same seg)
    int t0 = ((seg * 8) + ((tile & 1) << 2)) & 31;
    f16x8 evA, fvA, bA[4]; unsigned mA[4];
    f16x8 evB, fvB, bB[4]; unsigned mB[4];
    LOAD(evA, fvA, bA, mA, t0);

#pragma unroll 1
    for (int i = 0; i < 16; ++i) {
        const int t1 = (t0 + 1) & 31;
        LOAD(evB, fvB, bB, mB, t1);
        COMP(evA, fvA, bA, mA);
        const int t2 = (t0 + 2) & 31;
        LOAD(evA, fvA, bA, mA, t2);     // last one (i=15) is redundant, harmless
        COMP(evB, fvB, bB, mB);
        t0 = t2;
    }

    // complete per-row sums across the 4 quads (disjoint k coverage)
#pragma unroll
    for (int g = 0; g < 4; ++g) {
        lsum[g] += __shfl_xor(lsum[g], 16);
        lsum[g] += __shfl_xor(lsum[g], 32);
    }

    __syncthreads();   // mask reads done; st[] may be reused as stash

    auto stash = [&](int buf) {
#pragma unroll
        for (int g = 0; g < 4; ++g)
#pragma unroll
            for (int ot = 0; ot < 4; ++ot)
#pragma unroll
                for (int r = 0; r < 4; ++r)
                    st[buf][(g * 16 + quad * 4 + r) * 68 + ot * 16 + row16] = acc[g][ot][r];
        if (quad == 0)
#pragma unroll
            for (int g = 0; g < 4; ++g)
                lds_l[buf][g * 16 + row16] = lsum[g];
    };
    auto addin = [&](int buf) {
#pragma unroll
        for (int g = 0; g < 4; ++g) {
#pragma unroll
            for (int ot = 0; ot < 4; ++ot)
#pragma unroll
                for (int r = 0; r < 4; ++r)
                    acc[g][ot][r] += st[buf][(g * 16 + quad * 4 + r) * 68 + ot * 16 + row16];
            lsum[g] += lds_l[buf][g * 16 + row16];
        }
    };

    if (seg == 1) stash(0);
    if (seg == 3) stash(1);
    __syncthreads();
    if (seg == 0) addin(0);
    if (seg == 2) addin(1);
    __syncthreads();
    if (seg == 2) stash(0);
    __syncthreads();
    if (seg == 0) {
        addin(0);
        // epilogue: divide by l, ELU, deposit final 64x64 tile into st[0]
#pragma unroll
        for (int g = 0; g < 4; ++g)
#pragma unroll
            for (int r = 0; r < 4; ++r) {
                int   qr  = quad * 4 + r;
                float l   = __shfl(lsum[g], qr);    // lane qr holds row qr's sum
                float rl  = 1.0f / l;
#pragma unroll
                for (int ot = 0; ot < 4; ++ot) {
                    float v = acc[g][ot][r] * rl;
                    float y = v > 0.f ? v : __expf(v) - 1.f;
                    st[0][(g * 16 + qr) * 68 + ot * 16 + row16] = y;
                }
            }
    }
    __syncthreads();
    // cooperative coalesced store: 1024 float4s by 256 threads
#pragma unroll
    for (int p = 0; p < 4; ++p) {
        int f    = tid + p * 256;
        int row  = f >> 4;
        int col4 = (f & 15) * 4;
        float4 v = *(const float4*)&st[0][row * 68 + col4];
        *(float4*)&out[(size_t)(tile * 64 + row) * (HH * FOUT) + h * FOUT + col4] = v;
    }
}

// ---------------------------------------------------------------------------
extern "C" void kernel_launch(void* const* d_in, const int* in_sizes, int n_in,
                              void* d_out, int out_size, void* d_ws, size_t ws_size,
                              hipStream_t stream) {
    const float* features = (const float*)d_in[0];
    int*         adj      = (int*)d_in[1];
    const float* W        = (const float*)d_in[2];
    const float* a_src    = (const float*)d_in[3];
    const float* a_dst    = (const float*)d_in[4];
    float*       out      = (float*)d_out;

    char* ws = (char*)d_ws;
    __hip_bfloat16* WT   = (__hip_bfloat16*)(ws);                             // 512 KB (tiled)
    unsigned short* WhT  = (unsigned short*)(ws + (512 << 10));               // 4 MB (f16, tiled)
    float*          srcv = (float*)(ws + (512 << 10) + (4 << 20));            // 128 KB
    unsigned short* Ebf  = (unsigned short*)(ws + (512 << 10) + (4 << 20) + (128 << 10));  // 64 KB (f16)
    unsigned short* Fbf  = (unsigned short*)(ws + (512 << 10) + (4 << 20) + (192 << 10));  // 64 KB (f16)

    // packed mask: 2 MB in ws if it fits (keeps adj read-only); else in-place.
    const size_t mask_off = (512 << 10) + (4 << 20) + (256 << 10);            // 4.75 MB
    unsigned* maskp; int mstride;
    if (ws_size >= mask_off + (2u << 20)) {
        maskp   = (unsigned*)(ws + mask_off);
        mstride = 256;                         // contiguous: 256 dwords / row-pair
    } else {
        maskp   = (unsigned*)adj;              // in-place fallback (old layout)
        mstride = 8192;
    }

    k_transpose_w<<<dim3(64), 256, 0, stream>>>(W, WT);
    k_prep<<<dim3(2048 + 256), 256, 0, stream>>>(adj, maskp, mstride,
                                                 features, WT, a_src, a_dst,
                                                 WhT, srcv, Ebf, Fbf);
    k_flash<<<dim3(64, 8), 256, 0, stream>>>(maskp, mstride, srcv, Ebf, Fbf,
                                             WhT, out);
}